// Round 5
// baseline (1104.952 us; speedup 1.0000x reference)
//
#include <hip/hip_runtime.h>
#include <hip/hip_bf16.h>

typedef unsigned short u16;
typedef unsigned int   u32;

// Problem constants: B=4, S=2048, D=1024, H=16, HD=64
constexpr int B = 4, S = 2048, D = 1024, H = 16, HD = 64;
constexpr int M = B * S;                    // 8192
constexpr size_t TEN = (size_t)M * D;       // elems per q/k/v tensor (8.4M)

using bf16x8 = __attribute__((ext_vector_type(8))) short;
using f32x4  = __attribute__((ext_vector_type(4))) float;

__device__ __forceinline__ u16 f2bf(float f) {      // RNE f32 -> bf16
    u32 u = __float_as_uint(f);
    u += 0x7fffu + ((u >> 16) & 1u);
    return (u16)(u >> 16);
}
__device__ __forceinline__ u32 pack2(u16 a, u16 b) { return (u32)a | ((u32)b << 16); }

// ---------------------------------------------------------------------------
// Kernel 0: convert x -> (x_hi, x_lo) bf16 planes (exact residual split) and
// Wq|Wk|Wv -> bf16. One chunk of 8 elems per thread.
// ---------------------------------------------------------------------------
constexpr size_t NX8 = TEN / 8;             // 1,048,576 x-chunks
constexpr size_t NW8 = (size_t)D * D / 8;   // 131,072 chunks per W

__global__ __launch_bounds__(256) void convert_kernel(
    const float* __restrict__ x,
    const float* __restrict__ Wq, const float* __restrict__ Wk,
    const float* __restrict__ Wv,
    u16* __restrict__ xhi, u16* __restrict__ xlo, u16* __restrict__ wbf)
{
    size_t i = (size_t)blockIdx.x * 256 + threadIdx.x;
    if (i < NX8) {
        float4 f0 = *((const float4*)x + i * 2);
        float4 f1 = *((const float4*)x + i * 2 + 1);
        float f[8] = {f0.x, f0.y, f0.z, f0.w, f1.x, f1.y, f1.z, f1.w};
        u16 h[8], l[8];
        #pragma unroll
        for (int e = 0; e < 8; ++e) {
            h[e] = f2bf(f[e]);
            float hf = __uint_as_float((u32)h[e] << 16);
            l[e] = f2bf(f[e] - hf);
        }
        uint4 ho = make_uint4(pack2(h[0],h[1]), pack2(h[2],h[3]),
                              pack2(h[4],h[5]), pack2(h[6],h[7]));
        uint4 lo = make_uint4(pack2(l[0],l[1]), pack2(l[2],l[3]),
                              pack2(l[4],l[5]), pack2(l[6],l[7]));
        *(uint4*)(xhi + i * 8) = ho;
        *(uint4*)(xlo + i * 8) = lo;
    } else if (i < NX8 + 3 * NW8) {
        size_t j = i - NX8;
        const float* Wsrc;
        size_t jj;
        if (j < NW8)            { Wsrc = Wq; jj = j; }
        else if (j < 2 * NW8)   { Wsrc = Wk; jj = j - NW8; }
        else                    { Wsrc = Wv; jj = j - 2 * NW8; }
        float4 f0 = *((const float4*)Wsrc + jj * 2);
        float4 f1 = *((const float4*)Wsrc + jj * 2 + 1);
        float f[8] = {f0.x, f0.y, f0.z, f0.w, f1.x, f1.y, f1.z, f1.w};
        u16 h[8];
        #pragma unroll
        for (int e = 0; e < 8; ++e) h[e] = f2bf(f[e]);
        *(uint4*)(wbf + j * 8) = make_uint4(pack2(h[0],h[1]), pack2(h[2],h[3]),
                                            pack2(h[4],h[5]), pack2(h[6],h[7]));
    }
}

// ---------------------------------------------------------------------------
// Kernel 1: QKV projection via bf16 MFMA, x in hi+lo planes (2 MFMAs/k-frag,
// fp32 accumulate). Block: 128(M) x 64(N), BK=64, 4 waves each owning 32x64.
// Same NT fragment layout + XOR LDS swizzle as the attention kernel (proven).
// GBN=64=HD: one block = one head => v written directly transposed [bh][hd][s],
// killing the separate transpose kernel.
// ---------------------------------------------------------------------------
constexpr int GBM = 128, GBN = 64, GBK = 64;

__global__ __launch_bounds__(256, 2) void qkv_proj_kernel(
    const u16* __restrict__ xhi, const u16* __restrict__ xlo,
    const u16* __restrict__ wbf,
    const float* __restrict__ bq, const float* __restrict__ bk,
    const float* __restrict__ bv,
    u16* __restrict__ wsq, u16* __restrict__ wsk, u16* __restrict__ wvt)
{
    const int zi = blockIdx.z;
    const u16* __restrict__ Wz = wbf + (size_t)zi * D * D;
    const float* __restrict__ bias = (zi == 0) ? bq : (zi == 1) ? bk : bv;

    const int m0 = blockIdx.x * GBM;
    const int n0 = blockIdx.y * GBN;          // == h*64
    const int h  = blockIdx.y;
    const int tid = threadIdx.x;
    const int w = tid >> 6, lane = tid & 63;
    const int l15 = lane & 15, lg = lane >> 4;

    __shared__ __align__(16) u16 Ah[GBM * GBK];
    __shared__ __align__(16) u16 Al[GBM * GBK];
    __shared__ __align__(16) u16 Bs_[GBN * GBK];

    f32x4 acc[2][4];
    #pragma unroll
    for (int mi = 0; mi < 2; ++mi)
        #pragma unroll
        for (int ni = 0; ni < 4; ++ni) acc[mi][ni] = (f32x4){0.f,0.f,0.f,0.f};

    // staging geometry: chunk c -> row c>>3, slot c&7; c = tid + p*256.
    const int sl  = tid & 7;
    const int r_b = tid >> 3;                   // 0..31
    const int wsl8 = (sl ^ (r_b & 7)) * 8;      // swizzled 16B slot (row&7 inv. under +32)

    // prefetch k-tile 0
    uint4 ra[4], rl_[4], rb[2];
    #pragma unroll
    for (int p = 0; p < 4; ++p) {
        ra[p]  = *(const uint4*)(xhi + (size_t)(m0 + r_b + 32 * p) * D + sl * 8);
        rl_[p] = *(const uint4*)(xlo + (size_t)(m0 + r_b + 32 * p) * D + sl * 8);
    }
    #pragma unroll
    for (int p = 0; p < 2; ++p)
        rb[p] = *(const uint4*)(Wz + (size_t)(n0 + r_b + 32 * p) * D + sl * 8);

    for (int kt = 0; kt < D / GBK; ++kt) {
        #pragma unroll
        for (int p = 0; p < 4; ++p) {
            *(uint4*)&Ah[(r_b + 32 * p) * GBK + wsl8] = ra[p];
            *(uint4*)&Al[(r_b + 32 * p) * GBK + wsl8] = rl_[p];
        }
        #pragma unroll
        for (int p = 0; p < 2; ++p)
            *(uint4*)&Bs_[(r_b + 32 * p) * GBK + wsl8] = rb[p];
        __syncthreads();

        if (kt < D / GBK - 1) {
            const int k1 = (kt + 1) * GBK;
            #pragma unroll
            for (int p = 0; p < 4; ++p) {
                ra[p]  = *(const uint4*)(xhi + (size_t)(m0 + r_b + 32 * p) * D + k1 + sl * 8);
                rl_[p] = *(const uint4*)(xlo + (size_t)(m0 + r_b + 32 * p) * D + k1 + sl * 8);
            }
            #pragma unroll
            for (int p = 0; p < 2; ++p)
                rb[p] = *(const uint4*)(Wz + (size_t)(n0 + r_b + 32 * p) * D + k1 + sl * 8);
        }

        // B fragments (shared across mi)
        bf16x8 bf[4][2];
        #pragma unroll
        for (int ni = 0; ni < 4; ++ni) {
            int brow = ni * 16 + l15;
            #pragma unroll
            for (int kk = 0; kk < 2; ++kk)
                bf[ni][kk] = *(const bf16x8*)&Bs_[brow * GBK + ((kk * 4 + lg) ^ (brow & 7)) * 8];
        }
        #pragma unroll
        for (int mi = 0; mi < 2; ++mi) {
            int arow = w * 32 + mi * 16 + l15;
            bf16x8 ah[2], al[2];
            #pragma unroll
            for (int kk = 0; kk < 2; ++kk) {
                int so = ((kk * 4 + lg) ^ (arow & 7)) * 8;
                ah[kk] = *(const bf16x8*)&Ah[arow * GBK + so];
                al[kk] = *(const bf16x8*)&Al[arow * GBK + so];
            }
            #pragma unroll
            for (int ni = 0; ni < 4; ++ni) {
                #pragma unroll
                for (int kk = 0; kk < 2; ++kk) {
                    acc[mi][ni] = __builtin_amdgcn_mfma_f32_16x16x32_bf16(ah[kk], bf[ni][kk], acc[mi][ni], 0, 0, 0);
                    acc[mi][ni] = __builtin_amdgcn_mfma_f32_16x16x32_bf16(al[kk], bf[ni][kk], acc[mi][ni], 0, 0, 0);
                }
            }
        }
        __syncthreads();
    }

    // bias values for this thread's 4 column groups
    float bv4[4];
    #pragma unroll
    for (int ni = 0; ni < 4; ++ni) bv4[ni] = bias[n0 + ni * 16 + l15];

    if (zi < 2) {
        u16* __restrict__ dst = (zi == 0) ? wsq : wsk;
        #pragma unroll
        for (int mi = 0; mi < 2; ++mi) {
            #pragma unroll
            for (int r = 0; r < 4; ++r) {
                int m = m0 + w * 32 + mi * 16 + lg * 4 + r;
                int bb = m >> 11, s = m & 2047;
                u16* drow = dst + ((size_t)(bb * H + h) * S + s) * HD;
                #pragma unroll
                for (int ni = 0; ni < 4; ++ni)
                    drow[ni * 16 + l15] = f2bf(acc[mi][ni][r] + bv4[ni]);
            }
        }
    } else {
        // v -> transposed [bh][hd][s]; 4 consecutive s per lane -> uint2
        #pragma unroll
        for (int mi = 0; mi < 2; ++mi) {
            int mb = m0 + w * 32 + mi * 16 + lg * 4;
            int bb = mb >> 11, s0 = mb & 2047;
            #pragma unroll
            for (int ni = 0; ni < 4; ++ni) {
                int hd = ni * 16 + l15;
                u16 e0 = f2bf(acc[mi][ni][0] + bv4[ni]);
                u16 e1 = f2bf(acc[mi][ni][1] + bv4[ni]);
                u16 e2 = f2bf(acc[mi][ni][2] + bv4[ni]);
                u16 e3 = f2bf(acc[mi][ni][3] + bv4[ni]);
                *(uint2*)(wvt + ((size_t)(bb * H + h) * HD + hd) * S + s0) =
                    make_uint2(pack2(e0, e1), pack2(e2, e3));
            }
        }
    }
}

// ---------------------------------------------------------------------------
// Kernel 2: fused attention with bf16 MFMA (16x16x32). Unchanged from R4.
// ---------------------------------------------------------------------------
__global__ __launch_bounds__(256) void attn_fused_kernel(
    const u16* __restrict__ qg, const u16* __restrict__ kg,
    const u16* __restrict__ vtg, float* __restrict__ probs,
    float* __restrict__ out)
{
    const int bh = blockIdx.y;
    const int b = bh >> 4, h = bh & 15;
    const int m0 = blockIdx.x * 64;
    const int tid = threadIdx.x;
    const int w = tid >> 6, lane = tid & 63;
    const int l15 = lane & 15, lg = lane >> 4;

    const u16* __restrict__ qb  = qg  + (size_t)bh * S * HD;
    const u16* __restrict__ kbp = kg  + (size_t)bh * S * HD;
    const u16* __restrict__ vtb = vtg + (size_t)bh * HD * S;
    float* __restrict__ pb = probs + ((size_t)bh * S + m0) * (size_t)S;

    __shared__ __align__(16) u16 Ks[2][64 * 64];
    __shared__ __align__(16) u16 Vts[2][64 * 64];
    __shared__ __align__(16) float Es[64][68];

    bf16x8 aq[2];
    {
        const u16* qr = qb + (size_t)(m0 + w * 16 + l15) * HD + lg * 8;
        aq[0] = *(const bf16x8*)(qr);
        aq[1] = *(const bf16x8*)(qr + 32);
    }

    const int cid0 = tid, cid1 = tid + 256;
    const int r0 = cid0 >> 3, sl0 = cid0 & 7;
    const int r1 = cid1 >> 3, sl1 = cid1 & 7;
    const int wr0 = r0 * 64 + ((sl0 ^ (r0 & 7)) * 8);
    const int wr1 = r1 * 64 + ((sl1 ^ (r1 & 7)) * 8);

    // ------------------------- Pass A: row sums -------------------------
    float lacc[4] = {0.f, 0.f, 0.f, 0.f};
    uint4 ka, kc;
    ka = *(const uint4*)(kbp + cid0 * 8);
    kc = *(const uint4*)(kbp + cid1 * 8);
    *(uint4*)&Ks[0][wr0] = ka;
    *(uint4*)&Ks[0][wr1] = kc;
    __syncthreads();

    for (int t = 0; t < 32; ++t) {
        const int cur = t & 1;
        if (t < 31) {
            ka = *(const uint4*)(kbp + (size_t)(t + 1) * 4096 + cid0 * 8);
            kc = *(const uint4*)(kbp + (size_t)(t + 1) * 4096 + cid1 * 8);
        }
        f32x4 acc[4];
        #pragma unroll
        for (int n = 0; n < 4; ++n) acc[n] = (f32x4){0.f, 0.f, 0.f, 0.f};
        #pragma unroll
        for (int n = 0; n < 4; ++n) {
            #pragma unroll
            for (int kk = 0; kk < 2; ++kk) {
                int row = n * 16 + l15;
                int sl = (kk * 4 + lg) ^ (row & 7);
                bf16x8 bk_ = *(const bf16x8*)&Ks[cur][row * 64 + sl * 8];
                acc[n] = __builtin_amdgcn_mfma_f32_16x16x32_bf16(aq[kk], bk_, acc[n], 0, 0, 0);
            }
        }
        #pragma unroll
        for (int n = 0; n < 4; ++n)
            #pragma unroll
            for (int r = 0; r < 4; ++r)
                lacc[r] += __expf(acc[n][r]);
        if (t < 31) {
            *(uint4*)&Ks[cur ^ 1][wr0] = ka;
            *(uint4*)&Ks[cur ^ 1][wr1] = kc;
        }
        __syncthreads();
    }

    #pragma unroll
    for (int r = 0; r < 4; ++r) {
        lacc[r] += __shfl_xor(lacc[r], 1, 64);
        lacc[r] += __shfl_xor(lacc[r], 2, 64);
        lacc[r] += __shfl_xor(lacc[r], 4, 64);
        lacc[r] += __shfl_xor(lacc[r], 8, 64);
    }
    float inv_l[4];
    #pragma unroll
    for (int r = 0; r < 4; ++r) inv_l[r] = 1.f / lacc[r];

    // --------------------- Pass B: probs + PV ---------------------
    f32x4 accO[4];
    #pragma unroll
    for (int n = 0; n < 4; ++n) accO[n] = (f32x4){0.f, 0.f, 0.f, 0.f};

    uint4 va, vc;
    ka = *(const uint4*)(kbp + cid0 * 8);
    kc = *(const uint4*)(kbp + cid1 * 8);
    va = *(const uint4*)(vtb + (size_t)r0 * S + sl0 * 8);
    vc = *(const uint4*)(vtb + (size_t)r1 * S + sl1 * 8);
    *(uint4*)&Ks[0][wr0] = ka;  *(uint4*)&Ks[0][wr1] = kc;
    *(uint4*)&Vts[0][wr0] = va; *(uint4*)&Vts[0][wr1] = vc;
    __syncthreads();

    for (int t = 0; t < 32; ++t) {
        const int cur = t & 1;
        if (t < 31) {
            ka = *(const uint4*)(kbp + (size_t)(t + 1) * 4096 + cid0 * 8);
            kc = *(const uint4*)(kbp + (size_t)(t + 1) * 4096 + cid1 * 8);
            va = *(const uint4*)(vtb + (size_t)r0 * S + (t + 1) * 64 + sl0 * 8);
            vc = *(const uint4*)(vtb + (size_t)r1 * S + (t + 1) * 64 + sl1 * 8);
        }
        f32x4 acc[4];
        #pragma unroll
        for (int n = 0; n < 4; ++n) acc[n] = (f32x4){0.f, 0.f, 0.f, 0.f};
        #pragma unroll
        for (int n = 0; n < 4; ++n) {
            #pragma unroll
            for (int kk = 0; kk < 2; ++kk) {
                int row = n * 16 + l15;
                int sl = (kk * 4 + lg) ^ (row & 7);
                bf16x8 bk_ = *(const bf16x8*)&Ks[cur][row * 64 + sl * 8];
                acc[n] = __builtin_amdgcn_mfma_f32_16x16x32_bf16(aq[kk], bk_, acc[n], 0, 0, 0);
            }
        }
        #pragma unroll
        for (int n = 0; n < 4; ++n)
            #pragma unroll
            for (int r = 0; r < 4; ++r)
                Es[w * 16 + lg * 4 + r][n * 16 + l15] = __expf(acc[n][r]) * inv_l[r];

        {
            int rl = lane >> 2, c = lane & 3;
            const float* erow = &Es[w * 16 + rl][c * 16];
            float* prow = pb + (size_t)(w * 16 + rl) * S + t * 64 + c * 16;
            #pragma unroll
            for (int j = 0; j < 4; ++j)
                *(float4*)(prow + j * 4) = *(const float4*)(erow + j * 4);
        }

        bf16x8 af[2];
        #pragma unroll
        for (int kk2 = 0; kk2 < 2; ++kk2) {
            const float* e = &Es[w * 16 + l15][kk2 * 32 + lg * 8];
            float4 f0 = *(const float4*)(e);
            float4 f1 = *(const float4*)(e + 4);
            bf16x8 a_;
            a_[0] = (short)f2bf(f0.x); a_[1] = (short)f2bf(f0.y);
            a_[2] = (short)f2bf(f0.z); a_[3] = (short)f2bf(f0.w);
            a_[4] = (short)f2bf(f1.x); a_[5] = (short)f2bf(f1.y);
            a_[6] = (short)f2bf(f1.z); a_[7] = (short)f2bf(f1.w);
            af[kk2] = a_;
        }

        #pragma unroll
        for (int n = 0; n < 4; ++n) {
            #pragma unroll
            for (int kk2 = 0; kk2 < 2; ++kk2) {
                int row = n * 16 + l15;
                int sl = (kk2 * 4 + lg) ^ (row & 7);
                bf16x8 bv = *(const bf16x8*)&Vts[cur][row * 64 + sl * 8];
                accO[n] = __builtin_amdgcn_mfma_f32_16x16x32_bf16(af[kk2], bv, accO[n], 0, 0, 0);
            }
        }

        if (t < 31) {
            *(uint4*)&Ks[cur ^ 1][wr0] = ka;  *(uint4*)&Ks[cur ^ 1][wr1] = kc;
            *(uint4*)&Vts[cur ^ 1][wr0] = va; *(uint4*)&Vts[cur ^ 1][wr1] = vc;
        }
        __syncthreads();
    }

    #pragma unroll
    for (int n = 0; n < 4; ++n)
        #pragma unroll
        for (int r = 0; r < 4; ++r)
            out[((size_t)b * S + m0 + w * 16 + lg * 4 + r) * D + h * HD + n * 16 + l15] =
                accO[n][r];
}

// ---------------------------------------------------------------------------
extern "C" void kernel_launch(void* const* d_in, const int* in_sizes, int n_in,
                              void* d_out, int out_size, void* d_ws, size_t ws_size,
                              hipStream_t stream)
{
    const float* x  = (const float*)d_in[0];
    const float* Wq = (const float*)d_in[1];
    const float* bq = (const float*)d_in[2];
    const float* Wk = (const float*)d_in[3];
    const float* bk = (const float*)d_in[4];
    const float* Wv = (const float*)d_in[5];
    const float* bv = (const float*)d_in[6];

    float* out   = (float*)d_out;               // [B,S,D]
    float* probs = out + (size_t)B * S * D;     // [B,H,S,S]

    u16* wsq = (u16*)d_ws;                      // bf16 q [B,H,S,HD]
    u16* wsk = wsq + TEN;                       // bf16 k [B,H,S,HD]
    u16* wvt = wsk + TEN;                       // bf16 v^T [B,H,HD,S]
    u16* xhi = wvt + TEN;                       // bf16 x hi [M,D]
    u16* xlo = xhi + TEN;                       // bf16 x lo [M,D]
    u16* wbf = xlo + TEN;                       // bf16 Wq|Wk|Wv [3,D,D]
    (void)ws_size;                              // needs (5*TEN + 3*D*D)*2 ~= 90.5 MB

    dim3 gc((unsigned)((NX8 + 3 * NW8 + 255) / 256));
    convert_kernel<<<gc, 256, 0, stream>>>(x, Wq, Wk, Wv, xhi, xlo, wbf);

    dim3 g1(M / GBM, D / GBN, 3);
    qkv_proj_kernel<<<g1, 256, 0, stream>>>(xhi, xlo, wbf, bq, bk, bv, wsq, wsk, wvt);

    dim3 g2(S / 64, B * H);
    attn_fused_kernel<<<g2, 256, 0, stream>>>(wsq, wsk, wvt, probs, out);
}

// Round 6
// 644.946 us; speedup vs baseline: 1.7132x; 1.7132x over previous
//
#include <hip/hip_runtime.h>
#include <hip/hip_bf16.h>

typedef unsigned short u16;
typedef unsigned int   u32;

// Problem constants: B=4, S=2048, D=1024, H=16, HD=64
constexpr int B = 4, S = 2048, D = 1024, H = 16, HD = 64;
constexpr int M = B * S;                    // 8192
constexpr size_t TEN = (size_t)M * D;       // elems per q/k/v tensor (8.4M)

using bf16x8 = __attribute__((ext_vector_type(8))) short;
using f32x4  = __attribute__((ext_vector_type(4))) float;

__device__ __forceinline__ u16 f2bf(float f) {      // RNE f32 -> bf16
    u32 u = __float_as_uint(f);
    u += 0x7fffu + ((u >> 16) & 1u);
    return (u16)(u >> 16);
}
__device__ __forceinline__ u32 pack2(u16 a, u16 b) { return (u32)a | ((u32)b << 16); }

// Async global->LDS, 16B per lane. LDS dest must be the WAVE-UNIFORM base;
// HW writes lane i at base + i*16 (guide §5 caveat). Source addr is per-lane.
__device__ __forceinline__ void gll16(const u16* gsrc, u16* ldst) {
    __builtin_amdgcn_global_load_lds(
        (const __attribute__((address_space(1))) u32*)gsrc,
        (__attribute__((address_space(3))) u32*)ldst,
        16, 0, 0);
}

// ---------------------------------------------------------------------------
// Kernel 0: convert x -> (x_hi, x_lo) bf16 planes (exact residual split) and
// Wq|Wk|Wv -> bf16. One chunk of 8 elems per thread.
// ---------------------------------------------------------------------------
constexpr size_t NX8 = TEN / 8;             // 1,048,576 x-chunks
constexpr size_t NW8 = (size_t)D * D / 8;   // 131,072 chunks per W

__global__ __launch_bounds__(256) void convert_kernel(
    const float* __restrict__ x,
    const float* __restrict__ Wq, const float* __restrict__ Wk,
    const float* __restrict__ Wv,
    u16* __restrict__ xhi, u16* __restrict__ xlo, u16* __restrict__ wbf)
{
    size_t i = (size_t)blockIdx.x * 256 + threadIdx.x;
    if (i < NX8) {
        float4 f0 = *((const float4*)x + i * 2);
        float4 f1 = *((const float4*)x + i * 2 + 1);
        float f[8] = {f0.x, f0.y, f0.z, f0.w, f1.x, f1.y, f1.z, f1.w};
        u16 h[8], l[8];
        #pragma unroll
        for (int e = 0; e < 8; ++e) {
            h[e] = f2bf(f[e]);
            float hf = __uint_as_float((u32)h[e] << 16);
            l[e] = f2bf(f[e] - hf);
        }
        uint4 ho = make_uint4(pack2(h[0],h[1]), pack2(h[2],h[3]),
                              pack2(h[4],h[5]), pack2(h[6],h[7]));
        uint4 lo = make_uint4(pack2(l[0],l[1]), pack2(l[2],l[3]),
                              pack2(l[4],l[5]), pack2(l[6],l[7]));
        *(uint4*)(xhi + i * 8) = ho;
        *(uint4*)(xlo + i * 8) = lo;
    } else if (i < NX8 + 3 * NW8) {
        size_t j = i - NX8;
        const float* Wsrc;
        size_t jj;
        if (j < NW8)            { Wsrc = Wq; jj = j; }
        else if (j < 2 * NW8)   { Wsrc = Wk; jj = j - NW8; }
        else                    { Wsrc = Wv; jj = j - 2 * NW8; }
        float4 f0 = *((const float4*)Wsrc + jj * 2);
        float4 f1 = *((const float4*)Wsrc + jj * 2 + 1);
        float f[8] = {f0.x, f0.y, f0.z, f0.w, f1.x, f1.y, f1.z, f1.w};
        u16 h[8];
        #pragma unroll
        for (int e = 0; e < 8; ++e) h[e] = f2bf(f[e]);
        *(uint4*)(wbf + j * 8) = make_uint4(pack2(h[0],h[1]), pack2(h[2],h[3]),
                                            pack2(h[4],h[5]), pack2(h[6],h[7]));
    }
}

// ---------------------------------------------------------------------------
// Kernel 1: QKV projection via bf16 MFMA, x in hi+lo planes, fp32 accumulate.
// Block: 128(M) x 64(N), BK=32, 4 waves each owning 32x64. Staging via
// global_load_lds (linear LDS dest, inverse-swizzled per-lane source, rule
// #21); reads use slot = lg ^ (row&3). Double-buffered, 40KB LDS, no
// prefetch registers (R5's reg-staged version spilled under (256,2)).
// ---------------------------------------------------------------------------
constexpr int GBM = 128, GBN = 64, GBK = 32;
constexpr int NKT = D / GBK;                 // 32 k-tiles

__global__ __launch_bounds__(256, 2) void qkv_proj_kernel(
    const u16* __restrict__ xhi, const u16* __restrict__ xlo,
    const u16* __restrict__ wbf,
    const float* __restrict__ bq, const float* __restrict__ bk,
    const float* __restrict__ bv,
    u16* __restrict__ wsq, u16* __restrict__ wsk, u16* __restrict__ wvt)
{
    const int zi = blockIdx.z;
    const u16* __restrict__ Wz = wbf + (size_t)zi * D * D;
    const float* __restrict__ bias = (zi == 0) ? bq : (zi == 1) ? bk : bv;

    const int m0 = blockIdx.x * GBM;
    const int n0 = blockIdx.y * GBN;          // == h*64
    const int h  = blockIdx.y;
    const int tid = threadIdx.x;
    const int w = tid >> 6, lane = tid & 63;
    const int l15 = lane & 15, lg = lane >> 4;

    __shared__ __align__(16) u16 Ah[2][GBM * GBK];   // 2 x 8KB
    __shared__ __align__(16) u16 Al[2][GBM * GBK];   // 2 x 8KB
    __shared__ __align__(16) u16 Bt[2][GBN * GBK];   // 2 x 4KB

    const u16* __restrict__ xh_b = xhi + (size_t)m0 * D;
    const u16* __restrict__ xl_b = xlo + (size_t)m0 * D;
    const u16* __restrict__ wz_b = Wz + (size_t)n0 * D;

    f32x4 acc[2][4];
    #pragma unroll
    for (int mi = 0; mi < 2; ++mi)
        #pragma unroll
        for (int ni = 0; ni < 4; ++ni) acc[mi][ni] = (f32x4){0.f,0.f,0.f,0.f};

    // A tiles: 512 chunks (r=c>>2, s=c&3); wave w stages chunks w*128+p*64+lane.
    // B tile: 256 chunks; wave w stages chunks w*64+lane.
    auto stage = [&](int kt, int bb) {
        const int kofs = kt * GBK;
        #pragma unroll
        for (int p = 0; p < 2; ++p) {
            int c = w * 128 + p * 64 + lane;
            int r = c >> 2, s = c & 3;
            int sc = (s ^ (r & 3)) * 8;               // inverse swizzle on source
            const size_t go = (size_t)r * D + kofs + sc;
            gll16(xh_b + go, &Ah[bb][(w * 128 + p * 64) * 8]);
            gll16(xl_b + go, &Al[bb][(w * 128 + p * 64) * 8]);
        }
        int c = w * 64 + lane;
        int r = c >> 2, s = c & 3;
        int sc = (s ^ (r & 3)) * 8;
        gll16(wz_b + (size_t)r * D + kofs + sc, &Bt[bb][(w * 64) * 8]);
    };

    stage(0, 0);
    __syncthreads();

    for (int kt = 0; kt < NKT; ++kt) {
        const int cur = kt & 1;
        if (kt < NKT - 1) stage(kt + 1, cur ^ 1);

        bf16x8 bfr[4];
        #pragma unroll
        for (int ni = 0; ni < 4; ++ni) {
            int brow = ni * 16 + l15;
            bfr[ni] = *(const bf16x8*)&Bt[cur][brow * GBK + ((lg ^ (brow & 3)) * 8)];
        }
        #pragma unroll
        for (int mi = 0; mi < 2; ++mi) {
            int arow = w * 32 + mi * 16 + l15;
            int so = (lg ^ (arow & 3)) * 8;
            bf16x8 ah = *(const bf16x8*)&Ah[cur][arow * GBK + so];
            bf16x8 al = *(const bf16x8*)&Al[cur][arow * GBK + so];
            #pragma unroll
            for (int ni = 0; ni < 4; ++ni) {
                acc[mi][ni] = __builtin_amdgcn_mfma_f32_16x16x32_bf16(ah, bfr[ni], acc[mi][ni], 0, 0, 0);
                acc[mi][ni] = __builtin_amdgcn_mfma_f32_16x16x32_bf16(al, bfr[ni], acc[mi][ni], 0, 0, 0);
            }
        }
        __syncthreads();
    }

    float bv4[4];
    #pragma unroll
    for (int ni = 0; ni < 4; ++ni) bv4[ni] = bias[n0 + ni * 16 + l15];

    if (zi < 2) {
        u16* __restrict__ dst = (zi == 0) ? wsq : wsk;
        #pragma unroll
        for (int mi = 0; mi < 2; ++mi) {
            #pragma unroll
            for (int r = 0; r < 4; ++r) {
                int m = m0 + w * 32 + mi * 16 + lg * 4 + r;
                int bb = m >> 11, s = m & 2047;
                u16* drow = dst + ((size_t)(bb * H + h) * S + s) * HD;
                #pragma unroll
                for (int ni = 0; ni < 4; ++ni)
                    drow[ni * 16 + l15] = f2bf(acc[mi][ni][r] + bv4[ni]);
            }
        }
    } else {
        // v -> transposed [bh][hd][s]; 4 consecutive s per lane -> uint2
        #pragma unroll
        for (int mi = 0; mi < 2; ++mi) {
            int mb = m0 + w * 32 + mi * 16 + lg * 4;
            int bb = mb >> 11, s0 = mb & 2047;
            #pragma unroll
            for (int ni = 0; ni < 4; ++ni) {
                int hd = ni * 16 + l15;
                u16 e0 = f2bf(acc[mi][ni][0] + bv4[ni]);
                u16 e1 = f2bf(acc[mi][ni][1] + bv4[ni]);
                u16 e2 = f2bf(acc[mi][ni][2] + bv4[ni]);
                u16 e3 = f2bf(acc[mi][ni][3] + bv4[ni]);
                *(uint2*)(wvt + ((size_t)(bb * H + h) * HD + hd) * S + s0) =
                    make_uint2(pack2(e0, e1), pack2(e2, e3));
            }
        }
    }
}

// ---------------------------------------------------------------------------
// Kernel 2: fused attention with bf16 MFMA (16x16x32). Same math as R4/R5;
// staging switched to global_load_lds (linear dest + inverse-swizzled src).
// ---------------------------------------------------------------------------
__global__ __launch_bounds__(256) void attn_fused_kernel(
    const u16* __restrict__ qg, const u16* __restrict__ kg,
    const u16* __restrict__ vtg, float* __restrict__ probs,
    float* __restrict__ out)
{
    const int bh = blockIdx.y;
    const int b = bh >> 4, h = bh & 15;
    const int m0 = blockIdx.x * 64;
    const int tid = threadIdx.x;
    const int w = tid >> 6, lane = tid & 63;
    const int l15 = lane & 15, lg = lane >> 4;

    const u16* __restrict__ qb  = qg  + (size_t)bh * S * HD;
    const u16* __restrict__ kbp = kg  + (size_t)bh * S * HD;
    const u16* __restrict__ vtb = vtg + (size_t)bh * HD * S;
    float* __restrict__ pb = probs + ((size_t)bh * S + m0) * (size_t)S;

    __shared__ __align__(16) u16 Ks[2][64 * 64];
    __shared__ __align__(16) u16 Vts[2][64 * 64];
    __shared__ __align__(16) float Es[64][68];

    bf16x8 aq[2];
    {
        const u16* qr = qb + (size_t)(m0 + w * 16 + l15) * HD + lg * 8;
        aq[0] = *(const bf16x8*)(qr);
        aq[1] = *(const bf16x8*)(qr + 32);
    }

    // K/V tiles: 512 chunks (r=c>>3, s=c&7); wave w stages c = w*128+p*64+lane.
    auto stageK = [&](int t, int bb) {
        #pragma unroll
        for (int p = 0; p < 2; ++p) {
            int c = w * 128 + p * 64 + lane;
            int r = c >> 3, s = c & 7;
            int sc = (s ^ (r & 7)) * 8;
            gll16(kbp + (size_t)(t * 64 + r) * 64 + sc, &Ks[bb][(w * 128 + p * 64) * 8]);
        }
    };
    auto stageV = [&](int t, int bb) {
        #pragma unroll
        for (int p = 0; p < 2; ++p) {
            int c = w * 128 + p * 64 + lane;
            int r = c >> 3, s = c & 7;
            int sc = (s ^ (r & 7)) * 8;
            gll16(vtb + (size_t)r * S + t * 64 + sc, &Vts[bb][(w * 128 + p * 64) * 8]);
        }
    };

    // ------------------------- Pass A: row sums -------------------------
    float lacc[4] = {0.f, 0.f, 0.f, 0.f};
    stageK(0, 0);
    __syncthreads();

    for (int t = 0; t < 32; ++t) {
        const int cur = t & 1;
        if (t < 31) stageK(t + 1, cur ^ 1);
        f32x4 acc[4];
        #pragma unroll
        for (int n = 0; n < 4; ++n) acc[n] = (f32x4){0.f, 0.f, 0.f, 0.f};
        #pragma unroll
        for (int n = 0; n < 4; ++n) {
            #pragma unroll
            for (int kk = 0; kk < 2; ++kk) {
                int row = n * 16 + l15;
                int sl = (kk * 4 + lg) ^ (row & 7);
                bf16x8 bk_ = *(const bf16x8*)&Ks[cur][row * 64 + sl * 8];
                acc[n] = __builtin_amdgcn_mfma_f32_16x16x32_bf16(aq[kk], bk_, acc[n], 0, 0, 0);
            }
        }
        #pragma unroll
        for (int n = 0; n < 4; ++n)
            #pragma unroll
            for (int r = 0; r < 4; ++r)
                lacc[r] += __expf(acc[n][r]);
        __syncthreads();
    }

    #pragma unroll
    for (int r = 0; r < 4; ++r) {
        lacc[r] += __shfl_xor(lacc[r], 1, 64);
        lacc[r] += __shfl_xor(lacc[r], 2, 64);
        lacc[r] += __shfl_xor(lacc[r], 4, 64);
        lacc[r] += __shfl_xor(lacc[r], 8, 64);
    }
    float inv_l[4];
    #pragma unroll
    for (int r = 0; r < 4; ++r) inv_l[r] = 1.f / lacc[r];

    // --------------------- Pass B: probs + PV ---------------------
    f32x4 accO[4];
    #pragma unroll
    for (int n = 0; n < 4; ++n) accO[n] = (f32x4){0.f, 0.f, 0.f, 0.f};

    stageK(0, 0);
    stageV(0, 0);
    __syncthreads();

    for (int t = 0; t < 32; ++t) {
        const int cur = t & 1;
        if (t < 31) { stageK(t + 1, cur ^ 1); stageV(t + 1, cur ^ 1); }

        f32x4 acc[4];
        #pragma unroll
        for (int n = 0; n < 4; ++n) acc[n] = (f32x4){0.f, 0.f, 0.f, 0.f};
        #pragma unroll
        for (int n = 0; n < 4; ++n) {
            #pragma unroll
            for (int kk = 0; kk < 2; ++kk) {
                int row = n * 16 + l15;
                int sl = (kk * 4 + lg) ^ (row & 7);
                bf16x8 bk_ = *(const bf16x8*)&Ks[cur][row * 64 + sl * 8];
                acc[n] = __builtin_amdgcn_mfma_f32_16x16x32_bf16(aq[kk], bk_, acc[n], 0, 0, 0);
            }
        }
        #pragma unroll
        for (int n = 0; n < 4; ++n)
            #pragma unroll
            for (int r = 0; r < 4; ++r)
                Es[w * 16 + lg * 4 + r][n * 16 + l15] = __expf(acc[n][r]) * inv_l[r];

        {
            int rl = lane >> 2, c = lane & 3;
            const float* erow = &Es[w * 16 + rl][c * 16];
            float* prow = pb + (size_t)(w * 16 + rl) * S + t * 64 + c * 16;
            #pragma unroll
            for (int j = 0; j < 4; ++j)
                *(float4*)(prow + j * 4) = *(const float4*)(erow + j * 4);
        }

        bf16x8 af[2];
        #pragma unroll
        for (int kk2 = 0; kk2 < 2; ++kk2) {
            const float* e = &Es[w * 16 + l15][kk2 * 32 + lg * 8];
            float4 f0 = *(const float4*)(e);
            float4 f1 = *(const float4*)(e + 4);
            bf16x8 a_;
            a_[0] = (short)f2bf(f0.x); a_[1] = (short)f2bf(f0.y);
            a_[2] = (short)f2bf(f0.z); a_[3] = (short)f2bf(f0.w);
            a_[4] = (short)f2bf(f1.x); a_[5] = (short)f2bf(f1.y);
            a_[6] = (short)f2bf(f1.z); a_[7] = (short)f2bf(f1.w);
            af[kk2] = a_;
        }

        #pragma unroll
        for (int n = 0; n < 4; ++n) {
            #pragma unroll
            for (int kk2 = 0; kk2 < 2; ++kk2) {
                int row = n * 16 + l15;
                int sl = (kk2 * 4 + lg) ^ (row & 7);
                bf16x8 bv = *(const bf16x8*)&Vts[cur][row * 64 + sl * 8];
                accO[n] = __builtin_amdgcn_mfma_f32_16x16x32_bf16(af[kk2], bv, accO[n], 0, 0, 0);
            }
        }
        __syncthreads();
    }

    #pragma unroll
    for (int n = 0; n < 4; ++n)
        #pragma unroll
        for (int r = 0; r < 4; ++r)
            out[((size_t)b * S + m0 + w * 16 + lg * 4 + r) * D + h * HD + n * 16 + l15] =
                accO[n][r];
}

// ---------------------------------------------------------------------------
extern "C" void kernel_launch(void* const* d_in, const int* in_sizes, int n_in,
                              void* d_out, int out_size, void* d_ws, size_t ws_size,
                              hipStream_t stream)
{
    const float* x  = (const float*)d_in[0];
    const float* Wq = (const float*)d_in[1];
    const float* bq = (const float*)d_in[2];
    const float* Wk = (const float*)d_in[3];
    const float* bk = (const float*)d_in[4];
    const float* Wv = (const float*)d_in[5];
    const float* bv = (const float*)d_in[6];

    float* out   = (float*)d_out;               // [B,S,D]
    float* probs = out + (size_t)B * S * D;     // [B,H,S,S]

    u16* wsq = (u16*)d_ws;                      // bf16 q [B,H,S,HD]
    u16* wsk = wsq + TEN;                       // bf16 k [B,H,S,HD]
    u16* wvt = wsk + TEN;                       // bf16 v^T [B,H,HD,S]
    u16* xhi = wvt + TEN;                       // bf16 x hi [M,D]
    u16* xlo = xhi + TEN;                       // bf16 x lo [M,D]
    u16* wbf = xlo + TEN;                       // bf16 Wq|Wk|Wv [3,D,D]
    (void)ws_size;                              // needs (5*TEN + 3*D*D)*2 ~= 90.5 MB

    dim3 gc((unsigned)((NX8 + 3 * NW8 + 255) / 256));
    convert_kernel<<<gc, 256, 0, stream>>>(x, Wq, Wk, Wv, xhi, xlo, wbf);

    dim3 g1(M / GBM, D / GBN, 3);
    qkv_proj_kernel<<<g1, 256, 0, stream>>>(xhi, xlo, wbf, bq, bk, bv, wsq, wsk, wvt);

    dim3 g2(S / 64, B * H);
    attn_fused_kernel<<<g2, 256, 0, stream>>>(wsq, wsk, wvt, probs, out);
}

// Round 7
// 569.754 us; speedup vs baseline: 1.9393x; 1.1320x over previous
//
#include <hip/hip_runtime.h>
#include <hip/hip_bf16.h>

typedef unsigned short u16;
typedef unsigned int   u32;

// Problem constants: B=4, S=2048, D=1024, H=16, HD=64
constexpr int B = 4, S = 2048, D = 1024, H = 16, HD = 64;
constexpr int M = B * S;                    // 8192
constexpr size_t TEN = (size_t)M * D;       // elems per q/k/v tensor (8.4M)

using bf16x8 = __attribute__((ext_vector_type(8))) short;
using f32x4  = __attribute__((ext_vector_type(4))) float;

__device__ __forceinline__ u16 f2bf(float f) {      // RNE f32 -> bf16
    u32 u = __float_as_uint(f);
    u += 0x7fffu + ((u >> 16) & 1u);
    return (u16)(u >> 16);
}
__device__ __forceinline__ u32 pack2(u16 a, u16 b) { return (u32)a | ((u32)b << 16); }

// Async global->LDS, 16B per lane. LDS dest is the WAVE-UNIFORM base;
// HW writes lane i at base + i*16. Source addr is per-lane.
__device__ __forceinline__ void gll16(const u16* gsrc, u16* ldst) {
    __builtin_amdgcn_global_load_lds(
        (const __attribute__((address_space(1))) u32*)gsrc,
        (__attribute__((address_space(3))) u32*)ldst,
        16, 0, 0);
}

// ---------------------------------------------------------------------------
// Kernel 0: convert x -> (x_hi, x_lo) bf16 planes (exact residual split) and
// Wq|Wk|Wv -> bf16. Unchanged from R6.
// ---------------------------------------------------------------------------
constexpr size_t NX8 = TEN / 8;             // 1,048,576 x-chunks
constexpr size_t NW8 = (size_t)D * D / 8;   // 131,072 chunks per W

__global__ __launch_bounds__(256) void convert_kernel(
    const float* __restrict__ x,
    const float* __restrict__ Wq, const float* __restrict__ Wk,
    const float* __restrict__ Wv,
    u16* __restrict__ xhi, u16* __restrict__ xlo, u16* __restrict__ wbf)
{
    size_t i = (size_t)blockIdx.x * 256 + threadIdx.x;
    if (i < NX8) {
        float4 f0 = *((const float4*)x + i * 2);
        float4 f1 = *((const float4*)x + i * 2 + 1);
        float f[8] = {f0.x, f0.y, f0.z, f0.w, f1.x, f1.y, f1.z, f1.w};
        u16 h[8], l[8];
        #pragma unroll
        for (int e = 0; e < 8; ++e) {
            h[e] = f2bf(f[e]);
            float hf = __uint_as_float((u32)h[e] << 16);
            l[e] = f2bf(f[e] - hf);
        }
        uint4 ho = make_uint4(pack2(h[0],h[1]), pack2(h[2],h[3]),
                              pack2(h[4],h[5]), pack2(h[6],h[7]));
        uint4 lo = make_uint4(pack2(l[0],l[1]), pack2(l[2],l[3]),
                              pack2(l[4],l[5]), pack2(l[6],l[7]));
        *(uint4*)(xhi + i * 8) = ho;
        *(uint4*)(xlo + i * 8) = lo;
    } else if (i < NX8 + 3 * NW8) {
        size_t j = i - NX8;
        const float* Wsrc;
        size_t jj;
        if (j < NW8)            { Wsrc = Wq; jj = j; }
        else if (j < 2 * NW8)   { Wsrc = Wk; jj = j - NW8; }
        else                    { Wsrc = Wv; jj = j - 2 * NW8; }
        float4 f0 = *((const float4*)Wsrc + jj * 2);
        float4 f1 = *((const float4*)Wsrc + jj * 2 + 1);
        float f[8] = {f0.x, f0.y, f0.z, f0.w, f1.x, f1.y, f1.z, f1.w};
        u16 h[8];
        #pragma unroll
        for (int e = 0; e < 8; ++e) h[e] = f2bf(f[e]);
        *(uint4*)(wbf + j * 8) = make_uint4(pack2(h[0],h[1]), pack2(h[2],h[3]),
                                            pack2(h[4],h[5]), pack2(h[6],h[7]));
    }
}

// ---------------------------------------------------------------------------
// Kernel 1: QKV projection via bf16 MFMA (unchanged from R6).
// ---------------------------------------------------------------------------
constexpr int GBM = 128, GBN = 64, GBK = 32;
constexpr int NKT = D / GBK;                 // 32 k-tiles

__global__ __launch_bounds__(256, 2) void qkv_proj_kernel(
    const u16* __restrict__ xhi, const u16* __restrict__ xlo,
    const u16* __restrict__ wbf,
    const float* __restrict__ bq, const float* __restrict__ bk,
    const float* __restrict__ bv,
    u16* __restrict__ wsq, u16* __restrict__ wsk, u16* __restrict__ wvt)
{
    const int zi = blockIdx.z;
    const u16* __restrict__ Wz = wbf + (size_t)zi * D * D;
    const float* __restrict__ bias = (zi == 0) ? bq : (zi == 1) ? bk : bv;

    const int m0 = blockIdx.x * GBM;
    const int n0 = blockIdx.y * GBN;          // == h*64
    const int h  = blockIdx.y;
    const int tid = threadIdx.x;
    const int w = tid >> 6, lane = tid & 63;
    const int l15 = lane & 15, lg = lane >> 4;

    __shared__ __align__(16) u16 Ah[2][GBM * GBK];   // 2 x 8KB
    __shared__ __align__(16) u16 Al[2][GBM * GBK];   // 2 x 8KB
    __shared__ __align__(16) u16 Bt[2][GBN * GBK];   // 2 x 4KB

    const u16* __restrict__ xh_b = xhi + (size_t)m0 * D;
    const u16* __restrict__ xl_b = xlo + (size_t)m0 * D;
    const u16* __restrict__ wz_b = Wz + (size_t)n0 * D;

    f32x4 acc[2][4];
    #pragma unroll
    for (int mi = 0; mi < 2; ++mi)
        #pragma unroll
        for (int ni = 0; ni < 4; ++ni) acc[mi][ni] = (f32x4){0.f,0.f,0.f,0.f};

    auto stage = [&](int kt, int bb) {
        const int kofs = kt * GBK;
        #pragma unroll
        for (int p = 0; p < 2; ++p) {
            int c = w * 128 + p * 64 + lane;
            int r = c >> 2, s = c & 3;
            int sc = (s ^ (r & 3)) * 8;               // inverse swizzle on source
            const size_t go = (size_t)r * D + kofs + sc;
            gll16(xh_b + go, &Ah[bb][(w * 128 + p * 64) * 8]);
            gll16(xl_b + go, &Al[bb][(w * 128 + p * 64) * 8]);
        }
        int c = w * 64 + lane;
        int r = c >> 2, s = c & 3;
        int sc = (s ^ (r & 3)) * 8;
        gll16(wz_b + (size_t)r * D + kofs + sc, &Bt[bb][(w * 64) * 8]);
    };

    stage(0, 0);
    __syncthreads();

    for (int kt = 0; kt < NKT; ++kt) {
        const int cur = kt & 1;
        if (kt < NKT - 1) stage(kt + 1, cur ^ 1);

        bf16x8 bfr[4];
        #pragma unroll
        for (int ni = 0; ni < 4; ++ni) {
            int brow = ni * 16 + l15;
            bfr[ni] = *(const bf16x8*)&Bt[cur][brow * GBK + ((lg ^ (brow & 3)) * 8)];
        }
        #pragma unroll
        for (int mi = 0; mi < 2; ++mi) {
            int arow = w * 32 + mi * 16 + l15;
            int so = (lg ^ (arow & 3)) * 8;
            bf16x8 ah = *(const bf16x8*)&Ah[cur][arow * GBK + so];
            bf16x8 al = *(const bf16x8*)&Al[cur][arow * GBK + so];
            #pragma unroll
            for (int ni = 0; ni < 4; ++ni) {
                acc[mi][ni] = __builtin_amdgcn_mfma_f32_16x16x32_bf16(ah, bfr[ni], acc[mi][ni], 0, 0, 0);
                acc[mi][ni] = __builtin_amdgcn_mfma_f32_16x16x32_bf16(al, bfr[ni], acc[mi][ni], 0, 0, 0);
            }
        }
        __syncthreads();
    }

    float bv4[4];
    #pragma unroll
    for (int ni = 0; ni < 4; ++ni) bv4[ni] = bias[n0 + ni * 16 + l15];

    if (zi < 2) {
        u16* __restrict__ dst = (zi == 0) ? wsq : wsk;
        #pragma unroll
        for (int mi = 0; mi < 2; ++mi) {
            #pragma unroll
            for (int r = 0; r < 4; ++r) {
                int m = m0 + w * 32 + mi * 16 + lg * 4 + r;
                int bb = m >> 11, s = m & 2047;
                u16* drow = dst + ((size_t)(bb * H + h) * S + s) * HD;
                #pragma unroll
                for (int ni = 0; ni < 4; ++ni)
                    drow[ni * 16 + l15] = f2bf(acc[mi][ni][r] + bv4[ni]);
            }
        }
    } else {
        #pragma unroll
        for (int mi = 0; mi < 2; ++mi) {
            int mb = m0 + w * 32 + mi * 16 + lg * 4;
            int bb = mb >> 11, s0 = mb & 2047;
            #pragma unroll
            for (int ni = 0; ni < 4; ++ni) {
                int hd = ni * 16 + l15;
                u16 e0 = f2bf(acc[mi][ni][0] + bv4[ni]);
                u16 e1 = f2bf(acc[mi][ni][1] + bv4[ni]);
                u16 e2 = f2bf(acc[mi][ni][2] + bv4[ni]);
                u16 e3 = f2bf(acc[mi][ni][3] + bv4[ni]);
                *(uint2*)(wvt + ((size_t)(bb * H + h) * HD + hd) * S + s0) =
                    make_uint2(pack2(e0, e1), pack2(e2, e3));
            }
        }
    }
}

// ---------------------------------------------------------------------------
// Kernel 2: fused attention, bf16 MFMA, SWAPPED QK^T (computes S^T so q-row
// is lane-local: q = col = l15). Pass A: row sums with 15 adds + 2 shfl.
// Pass B: probs stored directly from regs (4 coalesced float4); PV A-frag
// built via wave-private 2KB P_lds (4 ds_write_b64 + 2 ds_read_b128,
// slot16^row&7 swizzle) -- replaces R6's Es transpose (16 b32 writes +
// 8 b128 reads + 4 dwordx4). PV and epilogue bit-identical to R6.
// ---------------------------------------------------------------------------
__global__ __launch_bounds__(256) void attn_fused_kernel(
    const u16* __restrict__ qg, const u16* __restrict__ kg,
    const u16* __restrict__ vtg, float* __restrict__ probs,
    float* __restrict__ out)
{
    const int bh = blockIdx.y;
    const int b = bh >> 4, h = bh & 15;
    const int m0 = blockIdx.x * 64;
    const int tid = threadIdx.x;
    const int w = tid >> 6, lane = tid & 63;
    const int l15 = lane & 15, lg = lane >> 4;

    const u16* __restrict__ qb  = qg  + (size_t)bh * S * HD;
    const u16* __restrict__ kbp = kg  + (size_t)bh * S * HD;
    const u16* __restrict__ vtb = vtg + (size_t)bh * HD * S;
    float* __restrict__ pb = probs + ((size_t)bh * S + m0) * (size_t)S;

    __shared__ __align__(16) u16 Ks[2][64 * 64];     // 16 KB
    __shared__ __align__(16) u16 Vts[2][64 * 64];    // 16 KB
    __shared__ __align__(16) u16 Pl[4][16 * 64];     // 8 KB, wave-private tiles

    bf16x8 aq[2];
    {
        const u16* qr = qb + (size_t)(m0 + w * 16 + l15) * HD + lg * 8;
        aq[0] = *(const bf16x8*)(qr);
        aq[1] = *(const bf16x8*)(qr + 32);
    }

    auto stageK = [&](int t, int bb) {
        #pragma unroll
        for (int p = 0; p < 2; ++p) {
            int c = w * 128 + p * 64 + lane;
            int r = c >> 3, s = c & 7;
            int sc = (s ^ (r & 7)) * 8;
            gll16(kbp + (size_t)(t * 64 + r) * 64 + sc, &Ks[bb][(w * 128 + p * 64) * 8]);
        }
    };
    auto stageV = [&](int t, int bb) {
        #pragma unroll
        for (int p = 0; p < 2; ++p) {
            int c = w * 128 + p * 64 + lane;
            int r = c >> 3, s = c & 7;
            int sc = (s ^ (r & 7)) * 8;
            gll16(vtb + (size_t)r * S + t * 64 + sc, &Vts[bb][(w * 128 + p * 64) * 8]);
        }
    };

    // ------------------------- Pass A: row sums -------------------------
    float lacc = 0.f;
    stageK(0, 0);
    __syncthreads();

    for (int t = 0; t < 32; ++t) {
        const int cur = t & 1;
        if (t < 31) stageK(t + 1, cur ^ 1);
        f32x4 acc[4];
        #pragma unroll
        for (int n = 0; n < 4; ++n) acc[n] = (f32x4){0.f, 0.f, 0.f, 0.f};
        #pragma unroll
        for (int n = 0; n < 4; ++n) {
            #pragma unroll
            for (int kk = 0; kk < 2; ++kk) {
                int row = n * 16 + l15;
                int sl = (kk * 4 + lg) ^ (row & 7);
                bf16x8 bk_ = *(const bf16x8*)&Ks[cur][row * 64 + sl * 8];
                // SWAPPED: A = K rows, B = Q rows -> D[k][q], q = col = l15
                acc[n] = __builtin_amdgcn_mfma_f32_16x16x32_bf16(bk_, aq[kk], acc[n], 0, 0, 0);
            }
        }
        #pragma unroll
        for (int n = 0; n < 4; ++n)
            #pragma unroll
            for (int r = 0; r < 4; ++r)
                lacc += __expf(acc[n][r]);
        __syncthreads();
    }

    lacc += __shfl_xor(lacc, 16, 64);
    lacc += __shfl_xor(lacc, 32, 64);
    const float inv_l = 1.f / lacc;          // row sum for q-row w*16+l15

    // --------------------- Pass B: probs + PV ---------------------
    f32x4 accO[4];
    #pragma unroll
    for (int n = 0; n < 4; ++n) accO[n] = (f32x4){0.f, 0.f, 0.f, 0.f};

    stageK(0, 0);
    stageV(0, 0);
    __syncthreads();

    float* pqrow = pb + (size_t)(w * 16 + l15) * S + lg * 4;   // this lane's q-row

    for (int t = 0; t < 32; ++t) {
        const int cur = t & 1;
        if (t < 31) { stageK(t + 1, cur ^ 1); stageV(t + 1, cur ^ 1); }

        f32x4 acc[4];
        #pragma unroll
        for (int n = 0; n < 4; ++n) acc[n] = (f32x4){0.f, 0.f, 0.f, 0.f};
        #pragma unroll
        for (int n = 0; n < 4; ++n) {
            #pragma unroll
            for (int kk = 0; kk < 2; ++kk) {
                int row = n * 16 + l15;
                int sl = (kk * 4 + lg) ^ (row & 7);
                bf16x8 bk_ = *(const bf16x8*)&Ks[cur][row * 64 + sl * 8];
                acc[n] = __builtin_amdgcn_mfma_f32_16x16x32_bf16(bk_, aq[kk], acc[n], 0, 0, 0);
            }
        }

        // p = exp(s)/l : lane owns q-row l15, k = t*64 + n*16 + lg*4 + r
        #pragma unroll
        for (int n = 0; n < 4; ++n) {
            float e0 = __expf(acc[n][0]) * inv_l;
            float e1 = __expf(acc[n][1]) * inv_l;
            float e2 = __expf(acc[n][2]) * inv_l;
            float e3 = __expf(acc[n][3]) * inv_l;
            float4 p4; p4.x = e0; p4.y = e1; p4.z = e2; p4.w = e3;
            *(float4*)(pqrow + t * 64 + n * 16) = p4;   // coalesced probs store
            // P_lds: row l15, k-span n*16+lg*4 (4 bf16 = 8B), slot16-swizzled
            uint2 pk2 = make_uint2(pack2(f2bf(e0), f2bf(e1)),
                                   pack2(f2bf(e2), f2bf(e3)));
            int s16 = (2 * n + (lg >> 1)) ^ (l15 & 7);
            *(uint2*)&Pl[w][l15 * 64 + s16 * 8 + (lg & 1) * 4] = pk2;
        }

        // PV A-frags straight from wave-private P_lds (row = q = l15)
        bf16x8 af[2];
        #pragma unroll
        for (int kk2 = 0; kk2 < 2; ++kk2) {
            int s16 = (kk2 * 4 + lg) ^ (l15 & 7);
            af[kk2] = *(const bf16x8*)&Pl[w][l15 * 64 + s16 * 8];
        }

        #pragma unroll
        for (int n = 0; n < 4; ++n) {
            #pragma unroll
            for (int kk2 = 0; kk2 < 2; ++kk2) {
                int row = n * 16 + l15;
                int sl = (kk2 * 4 + lg) ^ (row & 7);
                bf16x8 bv = *(const bf16x8*)&Vts[cur][row * 64 + sl * 8];
                accO[n] = __builtin_amdgcn_mfma_f32_16x16x32_bf16(af[kk2], bv, accO[n], 0, 0, 0);
            }
        }
        __syncthreads();
    }

    // epilogue: out[b][m0 + w*16 + lg*4 + r][h*64 + n*16 + l15]  (unchanged)
    #pragma unroll
    for (int n = 0; n < 4; ++n)
        #pragma unroll
        for (int r = 0; r < 4; ++r)
            out[((size_t)b * S + m0 + w * 16 + lg * 4 + r) * D + h * HD + n * 16 + l15] =
                accO[n][r];
}

// ---------------------------------------------------------------------------
extern "C" void kernel_launch(void* const* d_in, const int* in_sizes, int n_in,
                              void* d_out, int out_size, void* d_ws, size_t ws_size,
                              hipStream_t stream)
{
    const float* x  = (const float*)d_in[0];
    const float* Wq = (const float*)d_in[1];
    const float* bq = (const float*)d_in[2];
    const float* Wk = (const float*)d_in[3];
    const float* bk = (const float*)d_in[4];
    const float* Wv = (const float*)d_in[5];
    const float* bv = (const float*)d_in[6];

    float* out   = (float*)d_out;               // [B,S,D]
    float* probs = out + (size_t)B * S * D;     // [B,H,S,S]

    u16* wsq = (u16*)d_ws;                      // bf16 q [B,H,S,HD]
    u16* wsk = wsq + TEN;                       // bf16 k [B,H,S,HD]
    u16* wvt = wsk + TEN;                       // bf16 v^T [B,H,HD,S]
    u16* xhi = wvt + TEN;                       // bf16 x hi [M,D]
    u16* xlo = xhi + TEN;                       // bf16 x lo [M,D]
    u16* wbf = xlo + TEN;                       // bf16 Wq|Wk|Wv [3,D,D]
    (void)ws_size;                              // needs (5*TEN + 3*D*D)*2 ~= 90.5 MB

    dim3 gc((unsigned)((NX8 + 3 * NW8 + 255) / 256));
    convert_kernel<<<gc, 256, 0, stream>>>(x, Wq, Wk, Wv, xhi, xlo, wbf);

    dim3 g1(M / GBM, D / GBN, 3);
    qkv_proj_kernel<<<g1, 256, 0, stream>>>(xhi, xlo, wbf, bq, bk, bv, wsq, wsk, wvt);

    dim3 g2(S / 64, B * H);
    attn_fused_kernel<<<g2, 256, 0, stream>>>(wsq, wsk, wvt, probs, out);
}

// Round 8
// 528.030 us; speedup vs baseline: 2.0926x; 1.0790x over previous
//
#include <hip/hip_runtime.h>
#include <hip/hip_bf16.h>

typedef unsigned short u16;
typedef unsigned int   u32;

// Problem constants: B=4, S=2048, D=1024, H=16, HD=64
constexpr int B = 4, S = 2048, D = 1024, H = 16, HD = 64;
constexpr int M = B * S;                    // 8192
constexpr size_t TEN = (size_t)M * D;       // elems per q/k/v tensor (8.4M)

using bf16x8 = __attribute__((ext_vector_type(8))) short;
using f32x4  = __attribute__((ext_vector_type(4))) float;

__device__ __forceinline__ u16 f2bf(float f) {      // RNE f32 -> bf16
    u32 u = __float_as_uint(f);
    u += 0x7fffu + ((u >> 16) & 1u);
    return (u16)(u >> 16);
}
__device__ __forceinline__ u32 pack2(u16 a, u16 b) { return (u32)a | ((u32)b << 16); }

// Async global->LDS, 16B per lane. LDS dest is the WAVE-UNIFORM base;
// HW writes lane i at base + i*16. Source addr is per-lane.
__device__ __forceinline__ void gll16(const u16* gsrc, u16* ldst) {
    __builtin_amdgcn_global_load_lds(
        (const __attribute__((address_space(1))) u32*)gsrc,
        (__attribute__((address_space(3))) u32*)ldst,
        16, 0, 0);
}

// ---------------------------------------------------------------------------
// Kernel 0: convert x -> (x_hi, x_lo) bf16 planes (exact residual split) and
// Wq|Wk|Wv -> bf16. Unchanged from R6/R7.
// ---------------------------------------------------------------------------
constexpr size_t NX8 = TEN / 8;             // 1,048,576 x-chunks
constexpr size_t NW8 = (size_t)D * D / 8;   // 131,072 chunks per W

__global__ __launch_bounds__(256) void convert_kernel(
    const float* __restrict__ x,
    const float* __restrict__ Wq, const float* __restrict__ Wk,
    const float* __restrict__ Wv,
    u16* __restrict__ xhi, u16* __restrict__ xlo, u16* __restrict__ wbf)
{
    size_t i = (size_t)blockIdx.x * 256 + threadIdx.x;
    if (i < NX8) {
        float4 f0 = *((const float4*)x + i * 2);
        float4 f1 = *((const float4*)x + i * 2 + 1);
        float f[8] = {f0.x, f0.y, f0.z, f0.w, f1.x, f1.y, f1.z, f1.w};
        u16 h[8], l[8];
        #pragma unroll
        for (int e = 0; e < 8; ++e) {
            h[e] = f2bf(f[e]);
            float hf = __uint_as_float((u32)h[e] << 16);
            l[e] = f2bf(f[e] - hf);
        }
        uint4 ho = make_uint4(pack2(h[0],h[1]), pack2(h[2],h[3]),
                              pack2(h[4],h[5]), pack2(h[6],h[7]));
        uint4 lo = make_uint4(pack2(l[0],l[1]), pack2(l[2],l[3]),
                              pack2(l[4],l[5]), pack2(l[6],l[7]));
        *(uint4*)(xhi + i * 8) = ho;
        *(uint4*)(xlo + i * 8) = lo;
    } else if (i < NX8 + 3 * NW8) {
        size_t j = i - NX8;
        const float* Wsrc;
        size_t jj;
        if (j < NW8)            { Wsrc = Wq; jj = j; }
        else if (j < 2 * NW8)   { Wsrc = Wk; jj = j - NW8; }
        else                    { Wsrc = Wv; jj = j - 2 * NW8; }
        float4 f0 = *((const float4*)Wsrc + jj * 2);
        float4 f1 = *((const float4*)Wsrc + jj * 2 + 1);
        float f[8] = {f0.x, f0.y, f0.z, f0.w, f1.x, f1.y, f1.z, f1.w};
        u16 h[8];
        #pragma unroll
        for (int e = 0; e < 8; ++e) h[e] = f2bf(f[e]);
        *(uint4*)(wbf + j * 8) = make_uint4(pack2(h[0],h[1]), pack2(h[2],h[3]),
                                            pack2(h[4],h[5]), pack2(h[6],h[7]));
    }
}

// ---------------------------------------------------------------------------
// Kernel 1: QKV projection via bf16 MFMA. R8: GBN 64 -> 128 (halves x-plane
// tile traffic, 1.9 -> 1.2 GB). ni-loop split in two halves of 4 to keep
// B-fragment liveness low (stay under the 128-VGPR (256,2) cap). LDS
// patterns identical to R6 (A unchanged; B adopts A's 128x32 &3-XOR layout).
// ---------------------------------------------------------------------------
constexpr int GBM = 128, GBN = 128, GBK = 32;
constexpr int NKT = D / GBK;                 // 32 k-tiles

__global__ __launch_bounds__(256, 2) void qkv_proj_kernel(
    const u16* __restrict__ xhi, const u16* __restrict__ xlo,
    const u16* __restrict__ wbf,
    const float* __restrict__ bq, const float* __restrict__ bk,
    const float* __restrict__ bv,
    u16* __restrict__ wsq, u16* __restrict__ wsk, u16* __restrict__ wvt)
{
    const int zi = blockIdx.z;
    const u16* __restrict__ Wz = wbf + (size_t)zi * D * D;
    const float* __restrict__ bias = (zi == 0) ? bq : (zi == 1) ? bk : bv;

    const int m0 = blockIdx.x * GBM;
    const int n0 = blockIdx.y * GBN;          // spans heads n0/64 and n0/64+1
    const int h0 = n0 >> 6;
    const int tid = threadIdx.x;
    const int w = tid >> 6, lane = tid & 63;
    const int l15 = lane & 15, lg = lane >> 4;

    __shared__ __align__(16) u16 Ah[2][GBM * GBK];   // 2 x 8KB
    __shared__ __align__(16) u16 Al[2][GBM * GBK];   // 2 x 8KB
    __shared__ __align__(16) u16 Bt[2][GBN * GBK];   // 2 x 8KB

    const u16* __restrict__ xh_b = xhi + (size_t)m0 * D;
    const u16* __restrict__ xl_b = xlo + (size_t)m0 * D;
    const u16* __restrict__ wz_b = Wz + (size_t)n0 * D;

    f32x4 acc[2][8];
    #pragma unroll
    for (int mi = 0; mi < 2; ++mi)
        #pragma unroll
        for (int ni = 0; ni < 8; ++ni) acc[mi][ni] = (f32x4){0.f,0.f,0.f,0.f};

    // A: 512 chunks/plane (r=c>>2, s=c&3); B: 512 chunks; 2 per thread each.
    auto stage = [&](int kt, int bb) {
        const int kofs = kt * GBK;
        #pragma unroll
        for (int p = 0; p < 2; ++p) {
            int c = w * 128 + p * 64 + lane;
            int r = c >> 2, s = c & 3;
            int sc = (s ^ (r & 3)) * 8;               // inverse swizzle on source
            const size_t go = (size_t)r * D + kofs + sc;
            gll16(xh_b + go, &Ah[bb][(w * 128 + p * 64) * 8]);
            gll16(xl_b + go, &Al[bb][(w * 128 + p * 64) * 8]);
            gll16(wz_b + go, &Bt[bb][(w * 128 + p * 64) * 8]);
        }
    };

    stage(0, 0);
    __syncthreads();

    for (int kt = 0; kt < NKT; ++kt) {
        const int cur = kt & 1;
        if (kt < NKT - 1) stage(kt + 1, cur ^ 1);

        #pragma unroll
        for (int half = 0; half < 2; ++half) {
            bf16x8 bfr[4];
            #pragma unroll
            for (int ni4 = 0; ni4 < 4; ++ni4) {
                int brow = (half * 4 + ni4) * 16 + l15;
                bfr[ni4] = *(const bf16x8*)&Bt[cur][brow * GBK + ((lg ^ (brow & 3)) * 8)];
            }
            #pragma unroll
            for (int mi = 0; mi < 2; ++mi) {
                int arow = w * 32 + mi * 16 + l15;
                int so = (lg ^ (arow & 3)) * 8;
                bf16x8 ah = *(const bf16x8*)&Ah[cur][arow * GBK + so];
                bf16x8 al = *(const bf16x8*)&Al[cur][arow * GBK + so];
                #pragma unroll
                for (int ni4 = 0; ni4 < 4; ++ni4) {
                    acc[mi][half * 4 + ni4] = __builtin_amdgcn_mfma_f32_16x16x32_bf16(
                        ah, bfr[ni4], acc[mi][half * 4 + ni4], 0, 0, 0);
                    acc[mi][half * 4 + ni4] = __builtin_amdgcn_mfma_f32_16x16x32_bf16(
                        al, bfr[ni4], acc[mi][half * 4 + ni4], 0, 0, 0);
                }
            }
        }
        __syncthreads();
    }

    float bv8[8];
    #pragma unroll
    for (int ni = 0; ni < 8; ++ni) bv8[ni] = bias[n0 + ni * 16 + l15];

    if (zi < 2) {
        u16* __restrict__ dst = (zi == 0) ? wsq : wsk;
        #pragma unroll
        for (int mi = 0; mi < 2; ++mi) {
            #pragma unroll
            for (int r = 0; r < 4; ++r) {
                int m = m0 + w * 32 + mi * 16 + lg * 4 + r;
                int bb = m >> 11, s = m & 2047;
                #pragma unroll
                for (int ni = 0; ni < 8; ++ni) {
                    int h = h0 + (ni >> 2);
                    int hd = (ni & 3) * 16 + l15;
                    dst[((size_t)(bb * H + h) * S + s) * HD + hd] =
                        f2bf(acc[mi][ni][r] + bv8[ni]);
                }
            }
        }
    } else {
        // v -> transposed [bh][hd][s]; 4 consecutive s per lane -> uint2
        #pragma unroll
        for (int mi = 0; mi < 2; ++mi) {
            int mb = m0 + w * 32 + mi * 16 + lg * 4;
            int bb = mb >> 11, s0 = mb & 2047;
            #pragma unroll
            for (int ni = 0; ni < 8; ++ni) {
                int h = h0 + (ni >> 2);
                int hd = (ni & 3) * 16 + l15;
                u16 e0 = f2bf(acc[mi][ni][0] + bv8[ni]);
                u16 e1 = f2bf(acc[mi][ni][1] + bv8[ni]);
                u16 e2 = f2bf(acc[mi][ni][2] + bv8[ni]);
                u16 e3 = f2bf(acc[mi][ni][3] + bv8[ni]);
                *(uint2*)(wvt + ((size_t)(bb * H + h) * HD + hd) * S + s0) =
                    make_uint2(pack2(e0, e1), pack2(e2, e3));
            }
        }
    }
}

// ---------------------------------------------------------------------------
// Kernel 2: fused attention (R7 structure, swapped QK^T). R8 adds the
// bijective XCD swizzle (T1): 2048 blocks, 8 XCDs, 256 blocks each ->
// each XCD owns 8 consecutive bh's; K/V working set 4MB = one L2.
// ---------------------------------------------------------------------------
__global__ __launch_bounds__(256) void attn_fused_kernel(
    const u16* __restrict__ qg, const u16* __restrict__ kg,
    const u16* __restrict__ vtg, float* __restrict__ probs,
    float* __restrict__ out)
{
    // XCD-aware remap (nwg = 2048, divisible by 8 -> bijective)
    const int lin = blockIdx.y * gridDim.x + blockIdx.x;
    const int swz = (lin & 7) * 256 + (lin >> 3);
    const int bh = swz >> 5;
    const int m0 = (swz & 31) * 64;

    const int b = bh >> 4, h = bh & 15;
    const int tid = threadIdx.x;
    const int w = tid >> 6, lane = tid & 63;
    const int l15 = lane & 15, lg = lane >> 4;

    const u16* __restrict__ qb  = qg  + (size_t)bh * S * HD;
    const u16* __restrict__ kbp = kg  + (size_t)bh * S * HD;
    const u16* __restrict__ vtb = vtg + (size_t)bh * HD * S;
    float* __restrict__ pb = probs + ((size_t)bh * S + m0) * (size_t)S;

    __shared__ __align__(16) u16 Ks[2][64 * 64];     // 16 KB
    __shared__ __align__(16) u16 Vts[2][64 * 64];    // 16 KB
    __shared__ __align__(16) u16 Pl[4][16 * 64];     // 8 KB, wave-private tiles

    bf16x8 aq[2];
    {
        const u16* qr = qb + (size_t)(m0 + w * 16 + l15) * HD + lg * 8;
        aq[0] = *(const bf16x8*)(qr);
        aq[1] = *(const bf16x8*)(qr + 32);
    }

    auto stageK = [&](int t, int bb) {
        #pragma unroll
        for (int p = 0; p < 2; ++p) {
            int c = w * 128 + p * 64 + lane;
            int r = c >> 3, s = c & 7;
            int sc = (s ^ (r & 7)) * 8;
            gll16(kbp + (size_t)(t * 64 + r) * 64 + sc, &Ks[bb][(w * 128 + p * 64) * 8]);
        }
    };
    auto stageV = [&](int t, int bb) {
        #pragma unroll
        for (int p = 0; p < 2; ++p) {
            int c = w * 128 + p * 64 + lane;
            int r = c >> 3, s = c & 7;
            int sc = (s ^ (r & 7)) * 8;
            gll16(vtb + (size_t)r * S + t * 64 + sc, &Vts[bb][(w * 128 + p * 64) * 8]);
        }
    };

    // ------------------------- Pass A: row sums -------------------------
    float lacc = 0.f;
    stageK(0, 0);
    __syncthreads();

    for (int t = 0; t < 32; ++t) {
        const int cur = t & 1;
        if (t < 31) stageK(t + 1, cur ^ 1);
        f32x4 acc[4];
        #pragma unroll
        for (int n = 0; n < 4; ++n) acc[n] = (f32x4){0.f, 0.f, 0.f, 0.f};
        #pragma unroll
        for (int n = 0; n < 4; ++n) {
            #pragma unroll
            for (int kk = 0; kk < 2; ++kk) {
                int row = n * 16 + l15;
                int sl = (kk * 4 + lg) ^ (row & 7);
                bf16x8 bk_ = *(const bf16x8*)&Ks[cur][row * 64 + sl * 8];
                // SWAPPED: A = K rows, B = Q rows -> D[k][q], q = col = l15
                acc[n] = __builtin_amdgcn_mfma_f32_16x16x32_bf16(bk_, aq[kk], acc[n], 0, 0, 0);
            }
        }
        #pragma unroll
        for (int n = 0; n < 4; ++n)
            #pragma unroll
            for (int r = 0; r < 4; ++r)
                lacc += __expf(acc[n][r]);
        __syncthreads();
    }

    lacc += __shfl_xor(lacc, 16, 64);
    lacc += __shfl_xor(lacc, 32, 64);
    const float inv_l = 1.f / lacc;          // row sum for q-row w*16+l15

    // --------------------- Pass B: probs + PV ---------------------
    f32x4 accO[4];
    #pragma unroll
    for (int n = 0; n < 4; ++n) accO[n] = (f32x4){0.f, 0.f, 0.f, 0.f};

    stageK(0, 0);
    stageV(0, 0);
    __syncthreads();

    float* pqrow = pb + (size_t)(w * 16 + l15) * S + lg * 4;   // this lane's q-row

    for (int t = 0; t < 32; ++t) {
        const int cur = t & 1;
        if (t < 31) { stageK(t + 1, cur ^ 1); stageV(t + 1, cur ^ 1); }

        f32x4 acc[4];
        #pragma unroll
        for (int n = 0; n < 4; ++n) acc[n] = (f32x4){0.f, 0.f, 0.f, 0.f};
        #pragma unroll
        for (int n = 0; n < 4; ++n) {
            #pragma unroll
            for (int kk = 0; kk < 2; ++kk) {
                int row = n * 16 + l15;
                int sl = (kk * 4 + lg) ^ (row & 7);
                bf16x8 bk_ = *(const bf16x8*)&Ks[cur][row * 64 + sl * 8];
                acc[n] = __builtin_amdgcn_mfma_f32_16x16x32_bf16(bk_, aq[kk], acc[n], 0, 0, 0);
            }
        }

        // p = exp(s)/l : lane owns q-row l15, k = t*64 + n*16 + lg*4 + r
        #pragma unroll
        for (int n = 0; n < 4; ++n) {
            float e0 = __expf(acc[n][0]) * inv_l;
            float e1 = __expf(acc[n][1]) * inv_l;
            float e2 = __expf(acc[n][2]) * inv_l;
            float e3 = __expf(acc[n][3]) * inv_l;
            float4 p4; p4.x = e0; p4.y = e1; p4.z = e2; p4.w = e3;
            *(float4*)(pqrow + t * 64 + n * 16) = p4;   // coalesced probs store
            uint2 pk2 = make_uint2(pack2(f2bf(e0), f2bf(e1)),
                                   pack2(f2bf(e2), f2bf(e3)));
            int s16 = (2 * n + (lg >> 1)) ^ (l15 & 7);
            *(uint2*)&Pl[w][l15 * 64 + s16 * 8 + (lg & 1) * 4] = pk2;
        }

        // PV A-frags straight from wave-private P_lds (row = q = l15)
        bf16x8 af[2];
        #pragma unroll
        for (int kk2 = 0; kk2 < 2; ++kk2) {
            int s16 = (kk2 * 4 + lg) ^ (l15 & 7);
            af[kk2] = *(const bf16x8*)&Pl[w][l15 * 64 + s16 * 8];
        }

        #pragma unroll
        for (int n = 0; n < 4; ++n) {
            #pragma unroll
            for (int kk2 = 0; kk2 < 2; ++kk2) {
                int row = n * 16 + l15;
                int sl = (kk2 * 4 + lg) ^ (row & 7);
                bf16x8 bv = *(const bf16x8*)&Vts[cur][row * 64 + sl * 8];
                accO[n] = __builtin_amdgcn_mfma_f32_16x16x32_bf16(af[kk2], bv, accO[n], 0, 0, 0);
            }
        }
        __syncthreads();
    }

    // epilogue: out[b][m0 + w*16 + lg*4 + r][h*64 + n*16 + l15]
    #pragma unroll
    for (int n = 0; n < 4; ++n)
        #pragma unroll
        for (int r = 0; r < 4; ++r)
            out[((size_t)b * S + m0 + w * 16 + lg * 4 + r) * D + h * HD + n * 16 + l15] =
                accO[n][r];
}

// ---------------------------------------------------------------------------
extern "C" void kernel_launch(void* const* d_in, const int* in_sizes, int n_in,
                              void* d_out, int out_size, void* d_ws, size_t ws_size,
                              hipStream_t stream)
{
    const float* x  = (const float*)d_in[0];
    const float* Wq = (const float*)d_in[1];
    const float* bq = (const float*)d_in[2];
    const float* Wk = (const float*)d_in[3];
    const float* bk = (const float*)d_in[4];
    const float* Wv = (const float*)d_in[5];
    const float* bv = (const float*)d_in[6];

    float* out   = (float*)d_out;               // [B,S,D]
    float* probs = out + (size_t)B * S * D;     // [B,H,S,S]

    u16* wsq = (u16*)d_ws;                      // bf16 q [B,H,S,HD]
    u16* wsk = wsq + TEN;                       // bf16 k [B,H,S,HD]
    u16* wvt = wsk + TEN;                       // bf16 v^T [B,H,HD,S]
    u16* xhi = wvt + TEN;                       // bf16 x hi [M,D]
    u16* xlo = xhi + TEN;                       // bf16 x lo [M,D]
    u16* wbf = xlo + TEN;                       // bf16 Wq|Wk|Wv [3,D,D]
    (void)ws_size;                              // needs (5*TEN + 3*D*D)*2 ~= 90.5 MB

    dim3 gc((unsigned)((NX8 + 3 * NW8 + 255) / 256));
    convert_kernel<<<gc, 256, 0, stream>>>(x, Wq, Wk, Wv, xhi, xlo, wbf);

    dim3 g1(M / GBM, D / GBN, 3);
    qkv_proj_kernel<<<g1, 256, 0, stream>>>(xhi, xlo, wbf, bq, bk, bv, wsq, wsk, wvt);

    dim3 g2(S / 64, B * H);
    attn_fused_kernel<<<g2, 256, 0, stream>>>(wsq, wsk, wvt, probs, out);
}

// Round 9
// 509.221 us; speedup vs baseline: 2.1699x; 1.0369x over previous
//
#include <hip/hip_runtime.h>
#include <hip/hip_bf16.h>

typedef unsigned short u16;
typedef unsigned int   u32;

// Problem constants: B=4, S=2048, D=1024, H=16, HD=64
constexpr int B = 4, S = 2048, D = 1024, H = 16, HD = 64;
constexpr int M = B * S;                    // 8192
constexpr size_t TEN = (size_t)M * D;       // elems per q/k/v tensor (8.4M)

using bf16x8 = __attribute__((ext_vector_type(8))) short;
using f32x4  = __attribute__((ext_vector_type(4))) float;

__device__ __forceinline__ u16 f2bf(float f) {      // RNE f32 -> bf16
    u32 u = __float_as_uint(f);
    u += 0x7fffu + ((u >> 16) & 1u);
    return (u16)(u >> 16);
}
__device__ __forceinline__ u32 pack2(u16 a, u16 b) { return (u32)a | ((u32)b << 16); }

// Async global->LDS, 16B per lane. LDS dest is the WAVE-UNIFORM base;
// HW writes lane i at base + i*16. Source addr is per-lane.
__device__ __forceinline__ void gll16(const u16* gsrc, u16* ldst) {
    __builtin_amdgcn_global_load_lds(
        (const __attribute__((address_space(1))) u32*)gsrc,
        (__attribute__((address_space(3))) u32*)ldst,
        16, 0, 0);
}

// ---------------------------------------------------------------------------
// Kernel 0: convert x -> (x_hi, x_lo) bf16 planes (exact residual split) and
// Wq|Wk|Wv -> bf16. Unchanged from R6-R8.
// ---------------------------------------------------------------------------
constexpr size_t NX8 = TEN / 8;             // 1,048,576 x-chunks
constexpr size_t NW8 = (size_t)D * D / 8;   // 131,072 chunks per W

__global__ __launch_bounds__(256) void convert_kernel(
    const float* __restrict__ x,
    const float* __restrict__ Wq, const float* __restrict__ Wk,
    const float* __restrict__ Wv,
    u16* __restrict__ xhi, u16* __restrict__ xlo, u16* __restrict__ wbf)
{
    size_t i = (size_t)blockIdx.x * 256 + threadIdx.x;
    if (i < NX8) {
        float4 f0 = *((const float4*)x + i * 2);
        float4 f1 = *((const float4*)x + i * 2 + 1);
        float f[8] = {f0.x, f0.y, f0.z, f0.w, f1.x, f1.y, f1.z, f1.w};
        u16 h[8], l[8];
        #pragma unroll
        for (int e = 0; e < 8; ++e) {
            h[e] = f2bf(f[e]);
            float hf = __uint_as_float((u32)h[e] << 16);
            l[e] = f2bf(f[e] - hf);
        }
        uint4 ho = make_uint4(pack2(h[0],h[1]), pack2(h[2],h[3]),
                              pack2(h[4],h[5]), pack2(h[6],h[7]));
        uint4 lo = make_uint4(pack2(l[0],l[1]), pack2(l[2],l[3]),
                              pack2(l[4],l[5]), pack2(l[6],l[7]));
        *(uint4*)(xhi + i * 8) = ho;
        *(uint4*)(xlo + i * 8) = lo;
    } else if (i < NX8 + 3 * NW8) {
        size_t j = i - NX8;
        const float* Wsrc;
        size_t jj;
        if (j < NW8)            { Wsrc = Wq; jj = j; }
        else if (j < 2 * NW8)   { Wsrc = Wk; jj = j - NW8; }
        else                    { Wsrc = Wv; jj = j - 2 * NW8; }
        float4 f0 = *((const float4*)Wsrc + jj * 2);
        float4 f1 = *((const float4*)Wsrc + jj * 2 + 1);
        float f[8] = {f0.x, f0.y, f0.z, f0.w, f1.x, f1.y, f1.z, f1.w};
        u16 h[8];
        #pragma unroll
        for (int e = 0; e < 8; ++e) h[e] = f2bf(f[e]);
        *(uint4*)(wbf + j * 8) = make_uint4(pack2(h[0],h[1]), pack2(h[2],h[3]),
                                            pack2(h[4],h[5]), pack2(h[6],h[7]));
    }
}

// ---------------------------------------------------------------------------
// Kernel 1: QKV projection via bf16 MFMA (R8 math, unchanged). R9: 1D grid
// with explicit XCD-chunk mapping -- XCD k owns m-strips 8k..8k+7; within
// a chunk, (zi,ny) outer / m-strip inner, so 8 consecutive blocks share one
// W-strip and the 4MB A-strip set stays L2-resident. Cuts A-plane HBM
// traffic ~770MB -> ~80MB chip-wide.
// ---------------------------------------------------------------------------
constexpr int GBM = 128, GBN = 128, GBK = 32;
constexpr int NKT = D / GBK;                 // 32 k-tiles

__global__ __launch_bounds__(256, 2) void qkv_proj_kernel(
    const u16* __restrict__ xhi, const u16* __restrict__ xlo,
    const u16* __restrict__ wbf,
    const float* __restrict__ bq, const float* __restrict__ bk,
    const float* __restrict__ bv,
    u16* __restrict__ wsq, u16* __restrict__ wsk, u16* __restrict__ wvt)
{
    // XCD-chunk decode: lin%8 = XCD (round-robin dispatch assumption).
    const int lin    = blockIdx.x;            // 0..1535
    const int xcd    = lin & 7;
    const int local  = lin >> 3;              // 0..191
    const int wg     = local >> 3;            // 0..23 : (zi,ny)
    const int zi     = wg >> 3;               // 0..2
    const int ny     = wg & 7;                // 0..7
    const int mstrip = xcd * 8 + (local & 7); // 0..63

    const u16* __restrict__ Wz = wbf + (size_t)zi * D * D;
    const float* __restrict__ bias = (zi == 0) ? bq : (zi == 1) ? bk : bv;

    const int m0 = mstrip * GBM;
    const int n0 = ny * GBN;                  // spans heads n0/64, n0/64+1
    const int h0 = n0 >> 6;
    const int tid = threadIdx.x;
    const int w = tid >> 6, lane = tid & 63;
    const int l15 = lane & 15, lg = lane >> 4;

    __shared__ __align__(16) u16 Ah[2][GBM * GBK];   // 2 x 8KB
    __shared__ __align__(16) u16 Al[2][GBM * GBK];   // 2 x 8KB
    __shared__ __align__(16) u16 Bt[2][GBN * GBK];   // 2 x 8KB

    const u16* __restrict__ xh_b = xhi + (size_t)m0 * D;
    const u16* __restrict__ xl_b = xlo + (size_t)m0 * D;
    const u16* __restrict__ wz_b = Wz + (size_t)n0 * D;

    f32x4 acc[2][8];
    #pragma unroll
    for (int mi = 0; mi < 2; ++mi)
        #pragma unroll
        for (int ni = 0; ni < 8; ++ni) acc[mi][ni] = (f32x4){0.f,0.f,0.f,0.f};

    auto stage = [&](int kt, int bb) {
        const int kofs = kt * GBK;
        #pragma unroll
        for (int p = 0; p < 2; ++p) {
            int c = w * 128 + p * 64 + lane;
            int r = c >> 2, s = c & 3;
            int sc = (s ^ (r & 3)) * 8;               // inverse swizzle on source
            const size_t go = (size_t)r * D + kofs + sc;
            gll16(xh_b + go, &Ah[bb][(w * 128 + p * 64) * 8]);
            gll16(xl_b + go, &Al[bb][(w * 128 + p * 64) * 8]);
            gll16(wz_b + go, &Bt[bb][(w * 128 + p * 64) * 8]);
        }
    };

    stage(0, 0);
    __syncthreads();

    for (int kt = 0; kt < NKT; ++kt) {
        const int cur = kt & 1;
        if (kt < NKT - 1) stage(kt + 1, cur ^ 1);

        #pragma unroll
        for (int half = 0; half < 2; ++half) {
            bf16x8 bfr[4];
            #pragma unroll
            for (int ni4 = 0; ni4 < 4; ++ni4) {
                int brow = (half * 4 + ni4) * 16 + l15;
                bfr[ni4] = *(const bf16x8*)&Bt[cur][brow * GBK + ((lg ^ (brow & 3)) * 8)];
            }
            #pragma unroll
            for (int mi = 0; mi < 2; ++mi) {
                int arow = w * 32 + mi * 16 + l15;
                int so = (lg ^ (arow & 3)) * 8;
                bf16x8 ah = *(const bf16x8*)&Ah[cur][arow * GBK + so];
                bf16x8 al = *(const bf16x8*)&Al[cur][arow * GBK + so];
                #pragma unroll
                for (int ni4 = 0; ni4 < 4; ++ni4) {
                    acc[mi][half * 4 + ni4] = __builtin_amdgcn_mfma_f32_16x16x32_bf16(
                        ah, bfr[ni4], acc[mi][half * 4 + ni4], 0, 0, 0);
                    acc[mi][half * 4 + ni4] = __builtin_amdgcn_mfma_f32_16x16x32_bf16(
                        al, bfr[ni4], acc[mi][half * 4 + ni4], 0, 0, 0);
                }
            }
        }
        __syncthreads();
    }

    float bv8[8];
    #pragma unroll
    for (int ni = 0; ni < 8; ++ni) bv8[ni] = bias[n0 + ni * 16 + l15];

    if (zi < 2) {
        u16* __restrict__ dst = (zi == 0) ? wsq : wsk;
        #pragma unroll
        for (int mi = 0; mi < 2; ++mi) {
            #pragma unroll
            for (int r = 0; r < 4; ++r) {
                int m = m0 + w * 32 + mi * 16 + lg * 4 + r;
                int bb = m >> 11, s = m & 2047;
                #pragma unroll
                for (int ni = 0; ni < 8; ++ni) {
                    int h = h0 + (ni >> 2);
                    int hd = (ni & 3) * 16 + l15;
                    dst[((size_t)(bb * H + h) * S + s) * HD + hd] =
                        f2bf(acc[mi][ni][r] + bv8[ni]);
                }
            }
        }
    } else {
        // v -> transposed [bh][hd][s]; 4 consecutive s per lane -> uint2
        #pragma unroll
        for (int mi = 0; mi < 2; ++mi) {
            int mb = m0 + w * 32 + mi * 16 + lg * 4;
            int bb = mb >> 11, s0 = mb & 2047;
            #pragma unroll
            for (int ni = 0; ni < 8; ++ni) {
                int h = h0 + (ni >> 2);
                int hd = (ni & 3) * 16 + l15;
                u16 e0 = f2bf(acc[mi][ni][0] + bv8[ni]);
                u16 e1 = f2bf(acc[mi][ni][1] + bv8[ni]);
                u16 e2 = f2bf(acc[mi][ni][2] + bv8[ni]);
                u16 e3 = f2bf(acc[mi][ni][3] + bv8[ni]);
                *(uint2*)(wvt + ((size_t)(bb * H + h) * HD + hd) * S + s0) =
                    make_uint2(pack2(e0, e1), pack2(e2, e3));
            }
        }
    }
}

// ---------------------------------------------------------------------------
// Kernel 2: fused attention (R7/R8 math, swapped QK^T). R9: 8 waves / 512
// threads, QB=128 q-rows per block -- halves K/V staging ops and barriers
// per unit of work. Per-wave index math, swizzles, Pl path all unchanged.
// 1D grid of 1024 blocks with bijective XCD swizzle (chunk = 128).
// ---------------------------------------------------------------------------
__global__ __launch_bounds__(512) void attn_fused_kernel(
    const u16* __restrict__ qg, const u16* __restrict__ kg,
    const u16* __restrict__ vtg, float* __restrict__ probs,
    float* __restrict__ out)
{
    // XCD-aware remap (nwg = 1024, divisible by 8 -> bijective)
    const int lin = blockIdx.x;
    const int swz = (lin & 7) * 128 + (lin >> 3);
    const int bh = swz >> 4;                  // 16 q-blocks per bh
    const int m0 = (swz & 15) * 128;

    const int b = bh >> 4, h = bh & 15;
    const int tid = threadIdx.x;
    const int w = tid >> 6, lane = tid & 63;  // 8 waves
    const int l15 = lane & 15, lg = lane >> 4;

    const u16* __restrict__ qb  = qg  + (size_t)bh * S * HD;
    const u16* __restrict__ kbp = kg  + (size_t)bh * S * HD;
    const u16* __restrict__ vtb = vtg + (size_t)bh * HD * S;
    float* __restrict__ pb = probs + ((size_t)bh * S + m0) * (size_t)S;

    __shared__ __align__(16) u16 Ks[2][64 * 64];     // 16 KB
    __shared__ __align__(16) u16 Vts[2][64 * 64];    // 16 KB
    __shared__ __align__(16) u16 Pl[8][16 * 64];     // 16 KB, wave-private

    bf16x8 aq[2];
    {
        const u16* qr = qb + (size_t)(m0 + w * 16 + l15) * HD + lg * 8;
        aq[0] = *(const bf16x8*)(qr);
        aq[1] = *(const bf16x8*)(qr + 32);
    }

    // 512 chunks per 64x64 tile, 1 per thread; wave w stages chunks w*64+lane.
    auto stageK = [&](int t, int bb) {
        int c = w * 64 + lane;
        int r = c >> 3, s = c & 7;
        int sc = (s ^ (r & 7)) * 8;
        gll16(kbp + (size_t)(t * 64 + r) * 64 + sc, &Ks[bb][(w * 64) * 8]);
    };
    auto stageV = [&](int t, int bb) {
        int c = w * 64 + lane;
        int r = c >> 3, s = c & 7;
        int sc = (s ^ (r & 7)) * 8;
        gll16(vtb + (size_t)r * S + t * 64 + sc, &Vts[bb][(w * 64) * 8]);
    };

    // ------------------------- Pass A: row sums -------------------------
    float lacc = 0.f;
    stageK(0, 0);
    __syncthreads();

    for (int t = 0; t < 32; ++t) {
        const int cur = t & 1;
        if (t < 31) stageK(t + 1, cur ^ 1);
        f32x4 acc[4];
        #pragma unroll
        for (int n = 0; n < 4; ++n) acc[n] = (f32x4){0.f, 0.f, 0.f, 0.f};
        #pragma unroll
        for (int n = 0; n < 4; ++n) {
            #pragma unroll
            for (int kk = 0; kk < 2; ++kk) {
                int row = n * 16 + l15;
                int sl = (kk * 4 + lg) ^ (row & 7);
                bf16x8 bk_ = *(const bf16x8*)&Ks[cur][row * 64 + sl * 8];
                // SWAPPED: A = K rows, B = Q rows -> D[k][q], q = col = l15
                acc[n] = __builtin_amdgcn_mfma_f32_16x16x32_bf16(bk_, aq[kk], acc[n], 0, 0, 0);
            }
        }
        #pragma unroll
        for (int n = 0; n < 4; ++n)
            #pragma unroll
            for (int r = 0; r < 4; ++r)
                lacc += __expf(acc[n][r]);
        __syncthreads();
    }

    lacc += __shfl_xor(lacc, 16, 64);
    lacc += __shfl_xor(lacc, 32, 64);
    const float inv_l = 1.f / lacc;          // row sum for q-row w*16+l15

    // --------------------- Pass B: probs + PV ---------------------
    f32x4 accO[4];
    #pragma unroll
    for (int n = 0; n < 4; ++n) accO[n] = (f32x4){0.f, 0.f, 0.f, 0.f};

    stageK(0, 0);
    stageV(0, 0);
    __syncthreads();

    float* pqrow = pb + (size_t)(w * 16 + l15) * S + lg * 4;   // this lane's q-row

    for (int t = 0; t < 32; ++t) {
        const int cur = t & 1;
        if (t < 31) { stageK(t + 1, cur ^ 1); stageV(t + 1, cur ^ 1); }

        f32x4 acc[4];
        #pragma unroll
        for (int n = 0; n < 4; ++n) acc[n] = (f32x4){0.f, 0.f, 0.f, 0.f};
        #pragma unroll
        for (int n = 0; n < 4; ++n) {
            #pragma unroll
            for (int kk = 0; kk < 2; ++kk) {
                int row = n * 16 + l15;
                int sl = (kk * 4 + lg) ^ (row & 7);
                bf16x8 bk_ = *(const bf16x8*)&Ks[cur][row * 64 + sl * 8];
                acc[n] = __builtin_amdgcn_mfma_f32_16x16x32_bf16(bk_, aq[kk], acc[n], 0, 0, 0);
            }
        }

        // p = exp(s)/l : lane owns q-row l15, k = t*64 + n*16 + lg*4 + r
        #pragma unroll
        for (int n = 0; n < 4; ++n) {
            float e0 = __expf(acc[n][0]) * inv_l;
            float e1 = __expf(acc[n][1]) * inv_l;
            float e2 = __expf(acc[n][2]) * inv_l;
            float e3 = __expf(acc[n][3]) * inv_l;
            float4 p4; p4.x = e0; p4.y = e1; p4.z = e2; p4.w = e3;
            *(float4*)(pqrow + t * 64 + n * 16) = p4;   // coalesced probs store
            uint2 pk2 = make_uint2(pack2(f2bf(e0), f2bf(e1)),
                                   pack2(f2bf(e2), f2bf(e3)));
            int s16 = (2 * n + (lg >> 1)) ^ (l15 & 7);
            *(uint2*)&Pl[w][l15 * 64 + s16 * 8 + (lg & 1) * 4] = pk2;
        }

        // PV A-frags straight from wave-private P_lds (row = q = l15)
        bf16x8 af[2];
        #pragma unroll
        for (int kk2 = 0; kk2 < 2; ++kk2) {
            int s16 = (kk2 * 4 + lg) ^ (l15 & 7);
            af[kk2] = *(const bf16x8*)&Pl[w][l15 * 64 + s16 * 8];
        }

        #pragma unroll
        for (int n = 0; n < 4; ++n) {
            #pragma unroll
            for (int kk2 = 0; kk2 < 2; ++kk2) {
                int row = n * 16 + l15;
                int sl = (kk2 * 4 + lg) ^ (row & 7);
                bf16x8 bv = *(const bf16x8*)&Vts[cur][row * 64 + sl * 8];
                accO[n] = __builtin_amdgcn_mfma_f32_16x16x32_bf16(af[kk2], bv, accO[n], 0, 0, 0);
            }
        }
        __syncthreads();
    }

    // epilogue: out[b][m0 + w*16 + lg*4 + r][h*64 + n*16 + l15]
    #pragma unroll
    for (int n = 0; n < 4; ++n)
        #pragma unroll
        for (int r = 0; r < 4; ++r)
            out[((size_t)b * S + m0 + w * 16 + lg * 4 + r) * D + h * HD + n * 16 + l15] =
                accO[n][r];
}

// ---------------------------------------------------------------------------
extern "C" void kernel_launch(void* const* d_in, const int* in_sizes, int n_in,
                              void* d_out, int out_size, void* d_ws, size_t ws_size,
                              hipStream_t stream)
{
    const float* x  = (const float*)d_in[0];
    const float* Wq = (const float*)d_in[1];
    const float* bq = (const float*)d_in[2];
    const float* Wk = (const float*)d_in[3];
    const float* bk = (const float*)d_in[4];
    const float* Wv = (const float*)d_in[5];
    const float* bv = (const float*)d_in[6];

    float* out   = (float*)d_out;               // [B,S,D]
    float* probs = out + (size_t)B * S * D;     // [B,H,S,S]

    u16* wsq = (u16*)d_ws;                      // bf16 q [B,H,S,HD]
    u16* wsk = wsq + TEN;                       // bf16 k [B,H,S,HD]
    u16* wvt = wsk + TEN;                       // bf16 v^T [B,H,HD,S]
    u16* xhi = wvt + TEN;                       // bf16 x hi [M,D]
    u16* xlo = xhi + TEN;                       // bf16 x lo [M,D]
    u16* wbf = xlo + TEN;                       // bf16 Wq|Wk|Wv [3,D,D]
    (void)ws_size;                              // needs (5*TEN + 3*D*D)*2 ~= 90.5 MB

    dim3 gc((unsigned)((NX8 + 3 * NW8 + 255) / 256));
    convert_kernel<<<gc, 256, 0, stream>>>(x, Wq, Wk, Wv, xhi, xlo, wbf);

    qkv_proj_kernel<<<dim3(1536), 256, 0, stream>>>(xhi, xlo, wbf, bq, bk, bv,
                                                    wsq, wsk, wvt);

    attn_fused_kernel<<<dim3(1024), 512, 0, stream>>>(wsq, wsk, wvt, probs, out);
}

// Round 10
// 471.072 us; speedup vs baseline: 2.3456x; 1.0810x over previous
//
#include <hip/hip_runtime.h>
#include <hip/hip_bf16.h>

typedef unsigned short u16;
typedef unsigned int   u32;

// Problem constants: B=4, S=2048, D=1024, H=16, HD=64
constexpr int B = 4, S = 2048, D = 1024, H = 16, HD = 64;
constexpr int M = B * S;                    // 8192
constexpr size_t TEN = (size_t)M * D;       // elems per q/k/v tensor (8.4M)

using bf16x8 = __attribute__((ext_vector_type(8))) short;
using f32x4  = __attribute__((ext_vector_type(4))) float;

__device__ __forceinline__ u16 f2bf(float f) {      // RNE f32 -> bf16
    u32 u = __float_as_uint(f);
    u += 0x7fffu + ((u >> 16) & 1u);
    return (u16)(u >> 16);
}
__device__ __forceinline__ u32 pack2(u16 a, u16 b) { return (u32)a | ((u32)b << 16); }

// Async global->LDS, 16B per lane. LDS dest is the WAVE-UNIFORM base;
// HW writes lane i at base + i*16. Source addr is per-lane.
__device__ __forceinline__ void gll16(const u16* gsrc, u16* ldst) {
    __builtin_amdgcn_global_load_lds(
        (const __attribute__((address_space(1))) u32*)gsrc,
        (__attribute__((address_space(3))) u32*)ldst,
        16, 0, 0);
}

// ---------------------------------------------------------------------------
// Kernel 0: convert x -> (x_hi, x_lo) bf16 planes (exact residual split) and
// Wq|Wk|Wv -> bf16. Unchanged from R6-R9.
// ---------------------------------------------------------------------------
constexpr size_t NX8 = TEN / 8;             // 1,048,576 x-chunks
constexpr size_t NW8 = (size_t)D * D / 8;   // 131,072 chunks per W

__global__ __launch_bounds__(256) void convert_kernel(
    const float* __restrict__ x,
    const float* __restrict__ Wq, const float* __restrict__ Wk,
    const float* __restrict__ Wv,
    u16* __restrict__ xhi, u16* __restrict__ xlo, u16* __restrict__ wbf)
{
    size_t i = (size_t)blockIdx.x * 256 + threadIdx.x;
    if (i < NX8) {
        float4 f0 = *((const float4*)x + i * 2);
        float4 f1 = *((const float4*)x + i * 2 + 1);
        float f[8] = {f0.x, f0.y, f0.z, f0.w, f1.x, f1.y, f1.z, f1.w};
        u16 h[8], l[8];
        #pragma unroll
        for (int e = 0; e < 8; ++e) {
            h[e] = f2bf(f[e]);
            float hf = __uint_as_float((u32)h[e] << 16);
            l[e] = f2bf(f[e] - hf);
        }
        uint4 ho = make_uint4(pack2(h[0],h[1]), pack2(h[2],h[3]),
                              pack2(h[4],h[5]), pack2(h[6],h[7]));
        uint4 lo = make_uint4(pack2(l[0],l[1]), pack2(l[2],l[3]),
                              pack2(l[4],l[5]), pack2(l[6],l[7]));
        *(uint4*)(xhi + i * 8) = ho;
        *(uint4*)(xlo + i * 8) = lo;
    } else if (i < NX8 + 3 * NW8) {
        size_t j = i - NX8;
        const float* Wsrc;
        size_t jj;
        if (j < NW8)            { Wsrc = Wq; jj = j; }
        else if (j < 2 * NW8)   { Wsrc = Wk; jj = j - NW8; }
        else                    { Wsrc = Wv; jj = j - 2 * NW8; }
        float4 f0 = *((const float4*)Wsrc + jj * 2);
        float4 f1 = *((const float4*)Wsrc + jj * 2 + 1);
        float f[8] = {f0.x, f0.y, f0.z, f0.w, f1.x, f1.y, f1.z, f1.w};
        u16 h[8];
        #pragma unroll
        for (int e = 0; e < 8; ++e) h[e] = f2bf(f[e]);
        *(uint4*)(wbf + j * 8) = make_uint4(pack2(h[0],h[1]), pack2(h[2],h[3]),
                                            pack2(h[4],h[5]), pack2(h[6],h[7]));
    }
}

// ---------------------------------------------------------------------------
// Kernel 1: QKV projection via bf16 MFMA. Unchanged from R9 (XCD-chunk 1D
// grid; GBN=128; global_load_lds staging).
// ---------------------------------------------------------------------------
constexpr int GBM = 128, GBN = 128, GBK = 32;
constexpr int NKT = D / GBK;                 // 32 k-tiles

__global__ __launch_bounds__(256, 2) void qkv_proj_kernel(
    const u16* __restrict__ xhi, const u16* __restrict__ xlo,
    const u16* __restrict__ wbf,
    const float* __restrict__ bq, const float* __restrict__ bk,
    const float* __restrict__ bv,
    u16* __restrict__ wsq, u16* __restrict__ wsk, u16* __restrict__ wvt)
{
    const int lin    = blockIdx.x;            // 0..1535
    const int xcd    = lin & 7;
    const int local  = lin >> 3;              // 0..191
    const int wg     = local >> 3;            // 0..23 : (zi,ny)
    const int zi     = wg >> 3;               // 0..2
    const int ny     = wg & 7;                // 0..7
    const int mstrip = xcd * 8 + (local & 7); // 0..63

    const u16* __restrict__ Wz = wbf + (size_t)zi * D * D;
    const float* __restrict__ bias = (zi == 0) ? bq : (zi == 1) ? bk : bv;

    const int m0 = mstrip * GBM;
    const int n0 = ny * GBN;                  // spans heads n0/64, n0/64+1
    const int h0 = n0 >> 6;
    const int tid = threadIdx.x;
    const int w = tid >> 6, lane = tid & 63;
    const int l15 = lane & 15, lg = lane >> 4;

    __shared__ __align__(16) u16 Ah[2][GBM * GBK];   // 2 x 8KB
    __shared__ __align__(16) u16 Al[2][GBM * GBK];   // 2 x 8KB
    __shared__ __align__(16) u16 Bt[2][GBN * GBK];   // 2 x 8KB

    const u16* __restrict__ xh_b = xhi + (size_t)m0 * D;
    const u16* __restrict__ xl_b = xlo + (size_t)m0 * D;
    const u16* __restrict__ wz_b = Wz + (size_t)n0 * D;

    f32x4 acc[2][8];
    #pragma unroll
    for (int mi = 0; mi < 2; ++mi)
        #pragma unroll
        for (int ni = 0; ni < 8; ++ni) acc[mi][ni] = (f32x4){0.f,0.f,0.f,0.f};

    auto stage = [&](int kt, int bb) {
        const int kofs = kt * GBK;
        #pragma unroll
        for (int p = 0; p < 2; ++p) {
            int c = w * 128 + p * 64 + lane;
            int r = c >> 2, s = c & 3;
            int sc = (s ^ (r & 3)) * 8;               // inverse swizzle on source
            const size_t go = (size_t)r * D + kofs + sc;
            gll16(xh_b + go, &Ah[bb][(w * 128 + p * 64) * 8]);
            gll16(xl_b + go, &Al[bb][(w * 128 + p * 64) * 8]);
            gll16(wz_b + go, &Bt[bb][(w * 128 + p * 64) * 8]);
        }
    };

    stage(0, 0);
    __syncthreads();

    for (int kt = 0; kt < NKT; ++kt) {
        const int cur = kt & 1;
        if (kt < NKT - 1) stage(kt + 1, cur ^ 1);

        #pragma unroll
        for (int half = 0; half < 2; ++half) {
            bf16x8 bfr[4];
            #pragma unroll
            for (int ni4 = 0; ni4 < 4; ++ni4) {
                int brow = (half * 4 + ni4) * 16 + l15;
                bfr[ni4] = *(const bf16x8*)&Bt[cur][brow * GBK + ((lg ^ (brow & 3)) * 8)];
            }
            #pragma unroll
            for (int mi = 0; mi < 2; ++mi) {
                int arow = w * 32 + mi * 16 + l15;
                int so = (lg ^ (arow & 3)) * 8;
                bf16x8 ah = *(const bf16x8*)&Ah[cur][arow * GBK + so];
                bf16x8 al = *(const bf16x8*)&Al[cur][arow * GBK + so];
                #pragma unroll
                for (int ni4 = 0; ni4 < 4; ++ni4) {
                    acc[mi][half * 4 + ni4] = __builtin_amdgcn_mfma_f32_16x16x32_bf16(
                        ah, bfr[ni4], acc[mi][half * 4 + ni4], 0, 0, 0);
                    acc[mi][half * 4 + ni4] = __builtin_amdgcn_mfma_f32_16x16x32_bf16(
                        al, bfr[ni4], acc[mi][half * 4 + ni4], 0, 0, 0);
                }
            }
        }
        __syncthreads();
    }

    float bv8[8];
    #pragma unroll
    for (int ni = 0; ni < 8; ++ni) bv8[ni] = bias[n0 + ni * 16 + l15];

    if (zi < 2) {
        u16* __restrict__ dst = (zi == 0) ? wsq : wsk;
        #pragma unroll
        for (int mi = 0; mi < 2; ++mi) {
            #pragma unroll
            for (int r = 0; r < 4; ++r) {
                int m = m0 + w * 32 + mi * 16 + lg * 4 + r;
                int bb = m >> 11, s = m & 2047;
                #pragma unroll
                for (int ni = 0; ni < 8; ++ni) {
                    int h = h0 + (ni >> 2);
                    int hd = (ni & 3) * 16 + l15;
                    dst[((size_t)(bb * H + h) * S + s) * HD + hd] =
                        f2bf(acc[mi][ni][r] + bv8[ni]);
                }
            }
        }
    } else {
        #pragma unroll
        for (int mi = 0; mi < 2; ++mi) {
            int mb = m0 + w * 32 + mi * 16 + lg * 4;
            int bb = mb >> 11, s0 = mb & 2047;
            #pragma unroll
            for (int ni = 0; ni < 8; ++ni) {
                int h = h0 + (ni >> 2);
                int hd = (ni & 3) * 16 + l15;
                u16 e0 = f2bf(acc[mi][ni][0] + bv8[ni]);
                u16 e1 = f2bf(acc[mi][ni][1] + bv8[ni]);
                u16 e2 = f2bf(acc[mi][ni][2] + bv8[ni]);
                u16 e3 = f2bf(acc[mi][ni][3] + bv8[ni]);
                *(uint2*)(wvt + ((size_t)(bb * H + h) * HD + hd) * S + s0) =
                    make_uint2(pack2(e0, e1), pack2(e2, e3));
            }
        }
    }
}

// ---------------------------------------------------------------------------
// Kernel 2: fused attention (swapped QK^T, 2-pass). R10: QB=256, 16 waves /
// 1024 threads -- halves staging ops + barriers per unit of work again
// (waves 0-7 stage K, 8-15 stage V); T5 s_setprio(1) around MFMA clusters.
// Per-wave math/swizzles/Pl path unchanged from R7-R9. LDS 64KB, ~16
// waves/CU (one block) -- same wave occupancy as R9's 2x8-wave blocks.
// ---------------------------------------------------------------------------
__global__ __launch_bounds__(1024) void attn_fused_kernel(
    const u16* __restrict__ qg, const u16* __restrict__ kg,
    const u16* __restrict__ vtg, float* __restrict__ probs,
    float* __restrict__ out)
{
    // XCD-aware remap (nwg = 512, divisible by 8 -> bijective; chunk 64)
    const int lin = blockIdx.x;
    const int swz = (lin & 7) * 64 + (lin >> 3);
    const int bh = swz >> 3;                  // 8 q-blocks per bh
    const int m0 = (swz & 7) * 256;

    const int b = bh >> 4, h = bh & 15;
    const int tid = threadIdx.x;
    const int w = tid >> 6, lane = tid & 63;  // 16 waves
    const int l15 = lane & 15, lg = lane >> 4;

    const u16* __restrict__ qb  = qg  + (size_t)bh * S * HD;
    const u16* __restrict__ kbp = kg  + (size_t)bh * S * HD;
    const u16* __restrict__ vtb = vtg + (size_t)bh * HD * S;
    float* __restrict__ pb = probs + ((size_t)bh * S + m0) * (size_t)S;

    __shared__ __align__(16) u16 Ks[2][64 * 64];     // 16 KB
    __shared__ __align__(16) u16 Vts[2][64 * 64];    // 16 KB
    __shared__ __align__(16) u16 Pl[16][16 * 64];    // 32 KB, wave-private

    bf16x8 aq[2];
    {
        const u16* qr = qb + (size_t)(m0 + w * 16 + l15) * HD + lg * 8;
        aq[0] = *(const bf16x8*)(qr);
        aq[1] = *(const bf16x8*)(qr + 32);
    }

    // 512 chunks per 64x64 tile; waves 0-7 stage K (chunk w*64+lane),
    // waves 8-15 stage V (chunk (w-8)*64+lane).
    auto stageK = [&](int t, int bb) {
        if (w < 8) {
            int c = w * 64 + lane;
            int r = c >> 3, s = c & 7;
            int sc = (s ^ (r & 7)) * 8;
            gll16(kbp + (size_t)(t * 64 + r) * 64 + sc, &Ks[bb][(w * 64) * 8]);
        }
    };
    auto stageV = [&](int t, int bb) {
        if (w >= 8) {
            int c = (w - 8) * 64 + lane;
            int r = c >> 3, s = c & 7;
            int sc = (s ^ (r & 7)) * 8;
            gll16(vtb + (size_t)r * S + t * 64 + sc, &Vts[bb][((w - 8) * 64) * 8]);
        }
    };

    // ------------------------- Pass A: row sums -------------------------
    float lacc = 0.f;
    stageK(0, 0);
    __syncthreads();

    for (int t = 0; t < 32; ++t) {
        const int cur = t & 1;
        if (t < 31) stageK(t + 1, cur ^ 1);
        f32x4 acc[4];
        #pragma unroll
        for (int n = 0; n < 4; ++n) acc[n] = (f32x4){0.f, 0.f, 0.f, 0.f};
        __builtin_amdgcn_s_setprio(1);
        #pragma unroll
        for (int n = 0; n < 4; ++n) {
            #pragma unroll
            for (int kk = 0; kk < 2; ++kk) {
                int row = n * 16 + l15;
                int sl = (kk * 4 + lg) ^ (row & 7);
                bf16x8 bk_ = *(const bf16x8*)&Ks[cur][row * 64 + sl * 8];
                // SWAPPED: A = K rows, B = Q rows -> D[k][q], q = col = l15
                acc[n] = __builtin_amdgcn_mfma_f32_16x16x32_bf16(bk_, aq[kk], acc[n], 0, 0, 0);
            }
        }
        __builtin_amdgcn_s_setprio(0);
        #pragma unroll
        for (int n = 0; n < 4; ++n)
            #pragma unroll
            for (int r = 0; r < 4; ++r)
                lacc += __expf(acc[n][r]);
        __syncthreads();
    }

    lacc += __shfl_xor(lacc, 16, 64);
    lacc += __shfl_xor(lacc, 32, 64);
    const float inv_l = 1.f / lacc;          // row sum for q-row w*16+l15

    // --------------------- Pass B: probs + PV ---------------------
    f32x4 accO[4];
    #pragma unroll
    for (int n = 0; n < 4; ++n) accO[n] = (f32x4){0.f, 0.f, 0.f, 0.f};

    stageK(0, 0);
    stageV(0, 0);
    __syncthreads();

    float* pqrow = pb + (size_t)(w * 16 + l15) * S + lg * 4;   // this lane's q-row

    for (int t = 0; t < 32; ++t) {
        const int cur = t & 1;
        if (t < 31) { stageK(t + 1, cur ^ 1); stageV(t + 1, cur ^ 1); }

        f32x4 acc[4];
        #pragma unroll
        for (int n = 0; n < 4; ++n) acc[n] = (f32x4){0.f, 0.f, 0.f, 0.f};
        __builtin_amdgcn_s_setprio(1);
        #pragma unroll
        for (int n = 0; n < 4; ++n) {
            #pragma unroll
            for (int kk = 0; kk < 2; ++kk) {
                int row = n * 16 + l15;
                int sl = (kk * 4 + lg) ^ (row & 7);
                bf16x8 bk_ = *(const bf16x8*)&Ks[cur][row * 64 + sl * 8];
                acc[n] = __builtin_amdgcn_mfma_f32_16x16x32_bf16(bk_, aq[kk], acc[n], 0, 0, 0);
            }
        }
        __builtin_amdgcn_s_setprio(0);

        // p = exp(s)/l : lane owns q-row l15, k = t*64 + n*16 + lg*4 + r
        #pragma unroll
        for (int n = 0; n < 4; ++n) {
            float e0 = __expf(acc[n][0]) * inv_l;
            float e1 = __expf(acc[n][1]) * inv_l;
            float e2 = __expf(acc[n][2]) * inv_l;
            float e3 = __expf(acc[n][3]) * inv_l;
            float4 p4; p4.x = e0; p4.y = e1; p4.z = e2; p4.w = e3;
            *(float4*)(pqrow + t * 64 + n * 16) = p4;   // coalesced probs store
            uint2 pk2 = make_uint2(pack2(f2bf(e0), f2bf(e1)),
                                   pack2(f2bf(e2), f2bf(e3)));
            int s16 = (2 * n + (lg >> 1)) ^ (l15 & 7);
            *(uint2*)&Pl[w][l15 * 64 + s16 * 8 + (lg & 1) * 4] = pk2;
        }

        // PV A-frags straight from wave-private P_lds (row = q = l15)
        bf16x8 af[2];
        #pragma unroll
        for (int kk2 = 0; kk2 < 2; ++kk2) {
            int s16 = (kk2 * 4 + lg) ^ (l15 & 7);
            af[kk2] = *(const bf16x8*)&Pl[w][l15 * 64 + s16 * 8];
        }

        __builtin_amdgcn_s_setprio(1);
        #pragma unroll
        for (int n = 0; n < 4; ++n) {
            #pragma unroll
            for (int kk2 = 0; kk2 < 2; ++kk2) {
                int row = n * 16 + l15;
                int sl = (kk2 * 4 + lg) ^ (row & 7);
                bf16x8 bv = *(const bf16x8*)&Vts[cur][row * 64 + sl * 8];
                accO[n] = __builtin_amdgcn_mfma_f32_16x16x32_bf16(af[kk2], bv, accO[n], 0, 0, 0);
            }
        }
        __builtin_amdgcn_s_setprio(0);
        __syncthreads();
    }

    // epilogue: out[b][m0 + w*16 + lg*4 + r][h*64 + n*16 + l15]
    #pragma unroll
    for (int n = 0; n < 4; ++n)
        #pragma unroll
        for (int r = 0; r < 4; ++r)
            out[((size_t)b * S + m0 + w * 16 + lg * 4 + r) * D + h * HD + n * 16 + l15] =
                accO[n][r];
}

// ---------------------------------------------------------------------------
extern "C" void kernel_launch(void* const* d_in, const int* in_sizes, int n_in,
                              void* d_out, int out_size, void* d_ws, size_t ws_size,
                              hipStream_t stream)
{
    const float* x  = (const float*)d_in[0];
    const float* Wq = (const float*)d_in[1];
    const float* bq = (const float*)d_in[2];
    const float* Wk = (const float*)d_in[3];
    const float* bk = (const float*)d_in[4];
    const float* Wv = (const float*)d_in[5];
    const float* bv = (const float*)d_in[6];

    float* out   = (float*)d_out;               // [B,S,D]
    float* probs = out + (size_t)B * S * D;     // [B,H,S,S]

    u16* wsq = (u16*)d_ws;                      // bf16 q [B,H,S,HD]
    u16* wsk = wsq + TEN;                       // bf16 k [B,H,S,HD]
    u16* wvt = wsk + TEN;                       // bf16 v^T [B,H,HD,S]
    u16* xhi = wvt + TEN;                       // bf16 x hi [M,D]
    u16* xlo = xhi + TEN;                       // bf16 x lo [M,D]
    u16* wbf = xlo + TEN;                       // bf16 Wq|Wk|Wv [3,D,D]
    (void)ws_size;                              // needs (5*TEN + 3*D*D)*2 ~= 90.5 MB

    dim3 gc((unsigned)((NX8 + 3 * NW8 + 255) / 256));
    convert_kernel<<<gc, 256, 0, stream>>>(x, Wq, Wk, Wv, xhi, xlo, wbf);

    qkv_proj_kernel<<<dim3(1536), 256, 0, stream>>>(xhi, xlo, wbf, bq, bk, bv,
                                                    wsq, wsk, wvt);

    attn_fused_kernel<<<dim3(512), 1024, 0, stream>>>(wsq, wsk, wvt, probs, out);
}

// Round 12
// 462.269 us; speedup vs baseline: 2.3903x; 1.0190x over previous
//
#include <hip/hip_runtime.h>
#include <hip/hip_bf16.h>

typedef unsigned short u16;
typedef unsigned int   u32;

// Problem constants: B=4, S=2048, D=1024, H=16, HD=64
constexpr int B = 4, S = 2048, D = 1024, H = 16, HD = 64;
constexpr int M = B * S;                    // 8192
constexpr size_t TEN = (size_t)M * D;       // elems per q/k/v tensor (8.4M)

using bf16x8 = __attribute__((ext_vector_type(8))) short;
using f32x4  = __attribute__((ext_vector_type(4))) float;

__device__ __forceinline__ u16 f2bf(float f) {      // RNE f32 -> bf16
    u32 u = __float_as_uint(f);
    u += 0x7fffu + ((u >> 16) & 1u);
    return (u16)(u >> 16);
}
__device__ __forceinline__ u32 pack2(u16 a, u16 b) { return (u32)a | ((u32)b << 16); }

// Async global->LDS, 16B per lane. LDS dest is the WAVE-UNIFORM base;
// HW writes lane i at base + i*16. Source addr is per-lane.
__device__ __forceinline__ void gll16(const u16* gsrc, u16* ldst) {
    __builtin_amdgcn_global_load_lds(
        (const __attribute__((address_space(1))) u32*)gsrc,
        (__attribute__((address_space(3))) u32*)ldst,
        16, 0, 0);
}

// ---------------------------------------------------------------------------
// Kernel 0: convert x -> (x_hi, x_lo) bf16 planes (exact residual split) and
// Wq|Wk|Wv -> bf16. Unchanged from R6-R10.
// ---------------------------------------------------------------------------
constexpr size_t NX8 = TEN / 8;             // 1,048,576 x-chunks
constexpr size_t NW8 = (size_t)D * D / 8;   // 131,072 chunks per W

__global__ __launch_bounds__(256) void convert_kernel(
    const float* __restrict__ x,
    const float* __restrict__ Wq, const float* __restrict__ Wk,
    const float* __restrict__ Wv,
    u16* __restrict__ xhi, u16* __restrict__ xlo, u16* __restrict__ wbf)
{
    size_t i = (size_t)blockIdx.x * 256 + threadIdx.x;
    if (i < NX8) {
        float4 f0 = *((const float4*)x + i * 2);
        float4 f1 = *((const float4*)x + i * 2 + 1);
        float f[8] = {f0.x, f0.y, f0.z, f0.w, f1.x, f1.y, f1.z, f1.w};
        u16 h[8], l[8];
        #pragma unroll
        for (int e = 0; e < 8; ++e) {
            h[e] = f2bf(f[e]);
            float hf = __uint_as_float((u32)h[e] << 16);
            l[e] = f2bf(f[e] - hf);
        }
        uint4 ho = make_uint4(pack2(h[0],h[1]), pack2(h[2],h[3]),
                              pack2(h[4],h[5]), pack2(h[6],h[7]));
        uint4 lo = make_uint4(pack2(l[0],l[1]), pack2(l[2],l[3]),
                              pack2(l[4],l[5]), pack2(l[6],l[7]));
        *(uint4*)(xhi + i * 8) = ho;
        *(uint4*)(xlo + i * 8) = lo;
    } else if (i < NX8 + 3 * NW8) {
        size_t j = i - NX8;
        const float* Wsrc;
        size_t jj;
        if (j < NW8)            { Wsrc = Wq; jj = j; }
        else if (j < 2 * NW8)   { Wsrc = Wk; jj = j - NW8; }
        else                    { Wsrc = Wv; jj = j - 2 * NW8; }
        float4 f0 = *((const float4*)Wsrc + jj * 2);
        float4 f1 = *((const float4*)Wsrc + jj * 2 + 1);
        float f[8] = {f0.x, f0.y, f0.z, f0.w, f1.x, f1.y, f1.z, f1.w};
        u16 h[8];
        #pragma unroll
        for (int e = 0; e < 8; ++e) h[e] = f2bf(f[e]);
        *(uint4*)(wbf + j * 8) = make_uint4(pack2(h[0],h[1]), pack2(h[2],h[3]),
                                            pack2(h[4],h[5]), pack2(h[6],h[7]));
    }
}

// ---------------------------------------------------------------------------
// Kernel 1: QKV projection via bf16 MFMA (R9 math/grid). R12: launch_bounds
// (256,3) -> 3 blocks/CU (LDS 120KB of 160; VGPR cap ~170 >> ~110 used) so
// inter-block overlap hides the per-K-tile vmcnt(0)+barrier drain.
// ---------------------------------------------------------------------------
constexpr int GBM = 128, GBN = 128, GBK = 32;
constexpr int NKT = D / GBK;                 // 32 k-tiles

__global__ __launch_bounds__(256, 3) void qkv_proj_kernel(
    const u16* __restrict__ xhi, const u16* __restrict__ xlo,
    const u16* __restrict__ wbf,
    const float* __restrict__ bq, const float* __restrict__ bk,
    const float* __restrict__ bv,
    u16* __restrict__ wsq, u16* __restrict__ wsk, u16* __restrict__ wvt)
{
    const int lin    = blockIdx.x;            // 0..1535
    const int xcd    = lin & 7;
    const int local  = lin >> 3;              // 0..191
    const int wg     = local >> 3;            // 0..23 : (zi,ny)
    const int zi     = wg >> 3;               // 0..2
    const int ny     = wg & 7;                // 0..7
    const int mstrip = xcd * 8 + (local & 7); // 0..63

    const u16* __restrict__ Wz = wbf + (size_t)zi * D * D;
    const float* __restrict__ bias = (zi == 0) ? bq : (zi == 1) ? bk : bv;

    const int m0 = mstrip * GBM;
    const int n0 = ny * GBN;                  // spans heads n0/64, n0/64+1
    const int h0 = n0 >> 6;
    const int tid = threadIdx.x;
    const int w = tid >> 6, lane = tid & 63;
    const int l15 = lane & 15, lg = lane >> 4;

    __shared__ __align__(16) u16 Ah[2][GBM * GBK];   // 2 x 8KB
    __shared__ __align__(16) u16 Al[2][GBM * GBK];   // 2 x 8KB
    __shared__ __align__(16) u16 Bt[2][GBN * GBK];   // 2 x 8KB

    const u16* __restrict__ xh_b = xhi + (size_t)m0 * D;
    const u16* __restrict__ xl_b = xlo + (size_t)m0 * D;
    const u16* __restrict__ wz_b = Wz + (size_t)n0 * D;

    f32x4 acc[2][8];
    #pragma unroll
    for (int mi = 0; mi < 2; ++mi)
        #pragma unroll
        for (int ni = 0; ni < 8; ++ni) acc[mi][ni] = (f32x4){0.f,0.f,0.f,0.f};

    auto stage = [&](int kt, int bb) {
        const int kofs = kt * GBK;
        #pragma unroll
        for (int p = 0; p < 2; ++p) {
            int c = w * 128 + p * 64 + lane;
            int r = c >> 2, s = c & 3;
            int sc = (s ^ (r & 3)) * 8;               // inverse swizzle on source
            const size_t go = (size_t)r * D + kofs + sc;
            gll16(xh_b + go, &Ah[bb][(w * 128 + p * 64) * 8]);
            gll16(xl_b + go, &Al[bb][(w * 128 + p * 64) * 8]);
            gll16(wz_b + go, &Bt[bb][(w * 128 + p * 64) * 8]);
        }
    };

    stage(0, 0);
    __syncthreads();

    for (int kt = 0; kt < NKT; ++kt) {
        const int cur = kt & 1;
        if (kt < NKT - 1) stage(kt + 1, cur ^ 1);

        #pragma unroll
        for (int half = 0; half < 2; ++half) {
            bf16x8 bfr[4];
            #pragma unroll
            for (int ni4 = 0; ni4 < 4; ++ni4) {
                int brow = (half * 4 + ni4) * 16 + l15;
                bfr[ni4] = *(const bf16x8*)&Bt[cur][brow * GBK + ((lg ^ (brow & 3)) * 8)];
            }
            #pragma unroll
            for (int mi = 0; mi < 2; ++mi) {
                int arow = w * 32 + mi * 16 + l15;
                int so = (lg ^ (arow & 3)) * 8;
                bf16x8 ah = *(const bf16x8*)&Ah[cur][arow * GBK + so];
                bf16x8 al = *(const bf16x8*)&Al[cur][arow * GBK + so];
                #pragma unroll
                for (int ni4 = 0; ni4 < 4; ++ni4) {
                    acc[mi][half * 4 + ni4] = __builtin_amdgcn_mfma_f32_16x16x32_bf16(
                        ah, bfr[ni4], acc[mi][half * 4 + ni4], 0, 0, 0);
                    acc[mi][half * 4 + ni4] = __builtin_amdgcn_mfma_f32_16x16x32_bf16(
                        al, bfr[ni4], acc[mi][half * 4 + ni4], 0, 0, 0);
                }
            }
        }
        __syncthreads();
    }

    float bv8[8];
    #pragma unroll
    for (int ni = 0; ni < 8; ++ni) bv8[ni] = bias[n0 + ni * 16 + l15];

    if (zi < 2) {
        u16* __restrict__ dst = (zi == 0) ? wsq : wsk;
        #pragma unroll
        for (int mi = 0; mi < 2; ++mi) {
            #pragma unroll
            for (int r = 0; r < 4; ++r) {
                int m = m0 + w * 32 + mi * 16 + lg * 4 + r;
                int bb = m >> 11, s = m & 2047;
                #pragma unroll
                for (int ni = 0; ni < 8; ++ni) {
                    int h = h0 + (ni >> 2);
                    int hd = (ni & 3) * 16 + l15;
                    dst[((size_t)(bb * H + h) * S + s) * HD + hd] =
                        f2bf(acc[mi][ni][r] + bv8[ni]);
                }
            }
        }
    } else {
        #pragma unroll
        for (int mi = 0; mi < 2; ++mi) {
            int mb = m0 + w * 32 + mi * 16 + lg * 4;
            int bb = mb >> 11, s0 = mb & 2047;
            #pragma unroll
            for (int ni = 0; ni < 8; ++ni) {
                int h = h0 + (ni >> 2);
                int hd = (ni & 3) * 16 + l15;
                u16 e0 = f2bf(acc[mi][ni][0] + bv8[ni]);
                u16 e1 = f2bf(acc[mi][ni][1] + bv8[ni]);
                u16 e2 = f2bf(acc[mi][ni][2] + bv8[ni]);
                u16 e3 = f2bf(acc[mi][ni][3] + bv8[ni]);
                *(uint2*)(wvt + ((size_t)(bb * H + h) * HD + hd) * S + s0) =
                    make_uint2(pack2(e0, e1), pack2(e2, e3));
            }
        }
    }
}

// ---------------------------------------------------------------------------
// Kernel 2: fused attention (swapped QK^T, 2-pass, QB=256, 16 waves, T5
// setprio). R12: probs stores NONTEMPORAL via clang ext-vector f32x4
// (HIP float4 is a class type -> rejected by the builtin; that was R11's
// compile failure).
// ---------------------------------------------------------------------------
__global__ __launch_bounds__(1024) void attn_fused_kernel(
    const u16* __restrict__ qg, const u16* __restrict__ kg,
    const u16* __restrict__ vtg, float* __restrict__ probs,
    float* __restrict__ out)
{
    // XCD-aware remap (nwg = 512, divisible by 8 -> bijective; chunk 64)
    const int lin = blockIdx.x;
    const int swz = (lin & 7) * 64 + (lin >> 3);
    const int bh = swz >> 3;                  // 8 q-blocks per bh
    const int m0 = (swz & 7) * 256;

    const int b = bh >> 4, h = bh & 15;
    const int tid = threadIdx.x;
    const int w = tid >> 6, lane = tid & 63;  // 16 waves
    const int l15 = lane & 15, lg = lane >> 4;

    const u16* __restrict__ qb  = qg  + (size_t)bh * S * HD;
    const u16* __restrict__ kbp = kg  + (size_t)bh * S * HD;
    const u16* __restrict__ vtb = vtg + (size_t)bh * HD * S;
    float* __restrict__ pb = probs + ((size_t)bh * S + m0) * (size_t)S;

    __shared__ __align__(16) u16 Ks[2][64 * 64];     // 16 KB
    __shared__ __align__(16) u16 Vts[2][64 * 64];    // 16 KB
    __shared__ __align__(16) u16 Pl[16][16 * 64];    // 32 KB, wave-private

    bf16x8 aq[2];
    {
        const u16* qr = qb + (size_t)(m0 + w * 16 + l15) * HD + lg * 8;
        aq[0] = *(const bf16x8*)(qr);
        aq[1] = *(const bf16x8*)(qr + 32);
    }

    // 512 chunks per 64x64 tile; waves 0-7 stage K, waves 8-15 stage V.
    auto stageK = [&](int t, int bb) {
        if (w < 8) {
            int c = w * 64 + lane;
            int r = c >> 3, s = c & 7;
            int sc = (s ^ (r & 7)) * 8;
            gll16(kbp + (size_t)(t * 64 + r) * 64 + sc, &Ks[bb][(w * 64) * 8]);
        }
    };
    auto stageV = [&](int t, int bb) {
        if (w >= 8) {
            int c = (w - 8) * 64 + lane;
            int r = c >> 3, s = c & 7;
            int sc = (s ^ (r & 7)) * 8;
            gll16(vtb + (size_t)r * S + t * 64 + sc, &Vts[bb][((w - 8) * 64) * 8]);
        }
    };

    // ------------------------- Pass A: row sums -------------------------
    float lacc = 0.f;
    stageK(0, 0);
    __syncthreads();

    for (int t = 0; t < 32; ++t) {
        const int cur = t & 1;
        if (t < 31) stageK(t + 1, cur ^ 1);
        f32x4 acc[4];
        #pragma unroll
        for (int n = 0; n < 4; ++n) acc[n] = (f32x4){0.f, 0.f, 0.f, 0.f};
        __builtin_amdgcn_s_setprio(1);
        #pragma unroll
        for (int n = 0; n < 4; ++n) {
            #pragma unroll
            for (int kk = 0; kk < 2; ++kk) {
                int row = n * 16 + l15;
                int sl = (kk * 4 + lg) ^ (row & 7);
                bf16x8 bk_ = *(const bf16x8*)&Ks[cur][row * 64 + sl * 8];
                // SWAPPED: A = K rows, B = Q rows -> D[k][q], q = col = l15
                acc[n] = __builtin_amdgcn_mfma_f32_16x16x32_bf16(bk_, aq[kk], acc[n], 0, 0, 0);
            }
        }
        __builtin_amdgcn_s_setprio(0);
        #pragma unroll
        for (int n = 0; n < 4; ++n)
            #pragma unroll
            for (int r = 0; r < 4; ++r)
                lacc += __expf(acc[n][r]);
        __syncthreads();
    }

    lacc += __shfl_xor(lacc, 16, 64);
    lacc += __shfl_xor(lacc, 32, 64);
    const float inv_l = 1.f / lacc;          // row sum for q-row w*16+l15

    // --------------------- Pass B: probs + PV ---------------------
    f32x4 accO[4];
    #pragma unroll
    for (int n = 0; n < 4; ++n) accO[n] = (f32x4){0.f, 0.f, 0.f, 0.f};

    stageK(0, 0);
    stageV(0, 0);
    __syncthreads();

    float* pqrow = pb + (size_t)(w * 16 + l15) * S + lg * 4;   // this lane's q-row

    for (int t = 0; t < 32; ++t) {
        const int cur = t & 1;
        if (t < 31) { stageK(t + 1, cur ^ 1); stageV(t + 1, cur ^ 1); }

        f32x4 acc[4];
        #pragma unroll
        for (int n = 0; n < 4; ++n) acc[n] = (f32x4){0.f, 0.f, 0.f, 0.f};
        __builtin_amdgcn_s_setprio(1);
        #pragma unroll
        for (int n = 0; n < 4; ++n) {
            #pragma unroll
            for (int kk = 0; kk < 2; ++kk) {
                int row = n * 16 + l15;
                int sl = (kk * 4 + lg) ^ (row & 7);
                bf16x8 bk_ = *(const bf16x8*)&Ks[cur][row * 64 + sl * 8];
                acc[n] = __builtin_amdgcn_mfma_f32_16x16x32_bf16(bk_, aq[kk], acc[n], 0, 0, 0);
            }
        }
        __builtin_amdgcn_s_setprio(0);

        // p = exp(s)/l : lane owns q-row l15, k = t*64 + n*16 + lg*4 + r
        #pragma unroll
        for (int n = 0; n < 4; ++n) {
            float e0 = __expf(acc[n][0]) * inv_l;
            float e1 = __expf(acc[n][1]) * inv_l;
            float e2 = __expf(acc[n][2]) * inv_l;
            float e3 = __expf(acc[n][3]) * inv_l;
            f32x4 p4 = (f32x4){e0, e1, e2, e3};
            __builtin_nontemporal_store(p4, (f32x4*)(pqrow + t * 64 + n * 16));
            uint2 pk2 = make_uint2(pack2(f2bf(e0), f2bf(e1)),
                                   pack2(f2bf(e2), f2bf(e3)));
            int s16 = (2 * n + (lg >> 1)) ^ (l15 & 7);
            *(uint2*)&Pl[w][l15 * 64 + s16 * 8 + (lg & 1) * 4] = pk2;
        }

        // PV A-frags straight from wave-private P_lds (row = q = l15)
        bf16x8 af[2];
        #pragma unroll
        for (int kk2 = 0; kk2 < 2; ++kk2) {
            int s16 = (kk2 * 4 + lg) ^ (l15 & 7);
            af[kk2] = *(const bf16x8*)&Pl[w][l15 * 64 + s16 * 8];
        }

        __builtin_amdgcn_s_setprio(1);
        #pragma unroll
        for (int n = 0; n < 4; ++n) {
            #pragma unroll
            for (int kk2 = 0; kk2 < 2; ++kk2) {
                int row = n * 16 + l15;
                int sl = (kk2 * 4 + lg) ^ (row & 7);
                bf16x8 bv = *(const bf16x8*)&Vts[cur][row * 64 + sl * 8];
                accO[n] = __builtin_amdgcn_mfma_f32_16x16x32_bf16(af[kk2], bv, accO[n], 0, 0, 0);
            }
        }
        __builtin_amdgcn_s_setprio(0);
        __syncthreads();
    }

    // epilogue: out[b][m0 + w*16 + lg*4 + r][h*64 + n*16 + l15]
    #pragma unroll
    for (int n = 0; n < 4; ++n)
        #pragma unroll
        for (int r = 0; r < 4; ++r)
            out[((size_t)b * S + m0 + w * 16 + lg * 4 + r) * D + h * HD + n * 16 + l15] =
                accO[n][r];
}

// ---------------------------------------------------------------------------
extern "C" void kernel_launch(void* const* d_in, const int* in_sizes, int n_in,
                              void* d_out, int out_size, void* d_ws, size_t ws_size,
                              hipStream_t stream)
{
    const float* x  = (const float*)d_in[0];
    const float* Wq = (const float*)d_in[1];
    const float* bq = (const float*)d_in[2];
    const float* Wk = (const float*)d_in[3];
    const float* bk = (const float*)d_in[4];
    const float* Wv = (const float*)d_in[5];
    const float* bv = (const float*)d_in[6];

    float* out   = (float*)d_out;               // [B,S,D]
    float* probs = out + (size_t)B * S * D;     // [B,H,S,S]

    u16* wsq = (u16*)d_ws;                      // bf16 q [B,H,S,HD]
    u16* wsk = wsq + TEN;                       // bf16 k [B,H,S,HD]
    u16* wvt = wsk + TEN;                       // bf16 v^T [B,H,HD,S]
    u16* xhi = wvt + TEN;                       // bf16 x hi [M,D]
    u16* xlo = xhi + TEN;                       // bf16 x lo [M,D]
    u16* wbf = xlo + TEN;                       // bf16 Wq|Wk|Wv [3,D,D]
    (void)ws_size;                              // needs (5*TEN + 3*D*D)*2 ~= 90.5 MB

    dim3 gc((unsigned)((NX8 + 3 * NW8 + 255) / 256));
    convert_kernel<<<gc, 256, 0, stream>>>(x, Wq, Wk, Wv, xhi, xlo, wbf);

    qkv_proj_kernel<<<dim3(1536), 256, 0, stream>>>(xhi, xlo, wbf, bq, bk, bv,
                                                    wsq, wsk, wvt);

    attn_fused_kernel<<<dim3(512), 1024, 0, stream>>>(wsq, wsk, wvt, probs, out);
}

// Round 13
// 421.200 us; speedup vs baseline: 2.6233x; 1.0975x over previous
//
#include <hip/hip_runtime.h>
#include <hip/hip_bf16.h>

typedef unsigned short u16;
typedef unsigned int   u32;

// Problem constants: B=4, S=2048, D=1024, H=16, HD=64
constexpr int B = 4, S = 2048, D = 1024, H = 16, HD = 64;
constexpr int M = B * S;                    // 8192
constexpr size_t TEN = (size_t)M * D;       // elems per q/k/v tensor (8.4M)

using bf16x8 = __attribute__((ext_vector_type(8))) short;
using f32x4  = __attribute__((ext_vector_type(4))) float;

__device__ __forceinline__ u16 f2bf(float f) {      // RNE f32 -> bf16
    u32 u = __float_as_uint(f);
    u += 0x7fffu + ((u >> 16) & 1u);
    return (u16)(u >> 16);
}
__device__ __forceinline__ u32 pack2(u16 a, u16 b) { return (u32)a | ((u32)b << 16); }

// Async global->LDS, 16B per lane. LDS dest is the WAVE-UNIFORM base;
// HW writes lane i at base + i*16. Source addr is per-lane.
__device__ __forceinline__ void gll16(const u16* gsrc, u16* ldst) {
    __builtin_amdgcn_global_load_lds(
        (const __attribute__((address_space(1))) u32*)gsrc,
        (__attribute__((address_space(3))) u32*)ldst,
        16, 0, 0);
}

// ---------------------------------------------------------------------------
// Kernel 0: convert x -> bf16 (single plane; R13 drops the lo-residual --
// error budget allows it: predicted absmax ~0.04 < 0.0534) and
// Wq|Wk|Wv -> bf16.
// ---------------------------------------------------------------------------
constexpr size_t NX8 = TEN / 8;             // 1,048,576 x-chunks
constexpr size_t NW8 = (size_t)D * D / 8;   // 131,072 chunks per W

__global__ __launch_bounds__(256) void convert_kernel(
    const float* __restrict__ x,
    const float* __restrict__ Wq, const float* __restrict__ Wk,
    const float* __restrict__ Wv,
    u16* __restrict__ xbf, u16* __restrict__ wbf)
{
    size_t i = (size_t)blockIdx.x * 256 + threadIdx.x;
    if (i < NX8) {
        float4 f0 = *((const float4*)x + i * 2);
        float4 f1 = *((const float4*)x + i * 2 + 1);
        float f[8] = {f0.x, f0.y, f0.z, f0.w, f1.x, f1.y, f1.z, f1.w};
        u16 h[8];
        #pragma unroll
        for (int e = 0; e < 8; ++e) h[e] = f2bf(f[e]);
        *(uint4*)(xbf + i * 8) = make_uint4(pack2(h[0],h[1]), pack2(h[2],h[3]),
                                            pack2(h[4],h[5]), pack2(h[6],h[7]));
    } else if (i < NX8 + 3 * NW8) {
        size_t j = i - NX8;
        const float* Wsrc;
        size_t jj;
        if (j < NW8)            { Wsrc = Wq; jj = j; }
        else if (j < 2 * NW8)   { Wsrc = Wk; jj = j - NW8; }
        else                    { Wsrc = Wv; jj = j - 2 * NW8; }
        float4 f0 = *((const float4*)Wsrc + jj * 2);
        float4 f1 = *((const float4*)Wsrc + jj * 2 + 1);
        float f[8] = {f0.x, f0.y, f0.z, f0.w, f1.x, f1.y, f1.z, f1.w};
        u16 h[8];
        #pragma unroll
        for (int e = 0; e < 8; ++e) h[e] = f2bf(f[e]);
        *(uint4*)(wbf + j * 8) = make_uint4(pack2(h[0],h[1]), pack2(h[2],h[3]),
                                            pack2(h[4],h[5]), pack2(h[6],h[7]));
    }
}

// ---------------------------------------------------------------------------
// Kernel 1: QKV projection via bf16 MFMA. R13: single x plane (hi/lo split
// dropped) -- halves MFMA work (206->103 GF), staging 6->4 gll16/thread/tile,
// LDS 48->32KB. Grid/XCD mapping and all LDS patterns unchanged from R9-R12.
// ---------------------------------------------------------------------------
constexpr int GBM = 128, GBN = 128, GBK = 32;
constexpr int NKT = D / GBK;                 // 32 k-tiles

__global__ __launch_bounds__(256, 3) void qkv_proj_kernel(
    const u16* __restrict__ xbf, const u16* __restrict__ wbf,
    const float* __restrict__ bq, const float* __restrict__ bk,
    const float* __restrict__ bv,
    u16* __restrict__ wsq, u16* __restrict__ wsk, u16* __restrict__ wvt)
{
    const int lin    = blockIdx.x;            // 0..1535
    const int xcd    = lin & 7;
    const int local  = lin >> 3;              // 0..191
    const int wg     = local >> 3;            // 0..23 : (zi,ny)
    const int zi     = wg >> 3;               // 0..2
    const int ny     = wg & 7;                // 0..7
    const int mstrip = xcd * 8 + (local & 7); // 0..63

    const u16* __restrict__ Wz = wbf + (size_t)zi * D * D;
    const float* __restrict__ bias = (zi == 0) ? bq : (zi == 1) ? bk : bv;

    const int m0 = mstrip * GBM;
    const int n0 = ny * GBN;                  // spans heads n0/64, n0/64+1
    const int h0 = n0 >> 6;
    const int tid = threadIdx.x;
    const int w = tid >> 6, lane = tid & 63;
    const int l15 = lane & 15, lg = lane >> 4;

    __shared__ __align__(16) u16 Ah[2][GBM * GBK];   // 2 x 8KB
    __shared__ __align__(16) u16 Bt[2][GBN * GBK];   // 2 x 8KB

    const u16* __restrict__ xb_b = xbf + (size_t)m0 * D;
    const u16* __restrict__ wz_b = Wz + (size_t)n0 * D;

    f32x4 acc[2][8];
    #pragma unroll
    for (int mi = 0; mi < 2; ++mi)
        #pragma unroll
        for (int ni = 0; ni < 8; ++ni) acc[mi][ni] = (f32x4){0.f,0.f,0.f,0.f};

    auto stage = [&](int kt, int bb) {
        const int kofs = kt * GBK;
        #pragma unroll
        for (int p = 0; p < 2; ++p) {
            int c = w * 128 + p * 64 + lane;
            int r = c >> 2, s = c & 3;
            int sc = (s ^ (r & 3)) * 8;               // inverse swizzle on source
            const size_t go = (size_t)r * D + kofs + sc;
            gll16(xb_b + go, &Ah[bb][(w * 128 + p * 64) * 8]);
            gll16(wz_b + go, &Bt[bb][(w * 128 + p * 64) * 8]);
        }
    };

    stage(0, 0);
    __syncthreads();

    for (int kt = 0; kt < NKT; ++kt) {
        const int cur = kt & 1;
        if (kt < NKT - 1) stage(kt + 1, cur ^ 1);

        #pragma unroll
        for (int half = 0; half < 2; ++half) {
            bf16x8 bfr[4];
            #pragma unroll
            for (int ni4 = 0; ni4 < 4; ++ni4) {
                int brow = (half * 4 + ni4) * 16 + l15;
                bfr[ni4] = *(const bf16x8*)&Bt[cur][brow * GBK + ((lg ^ (brow & 3)) * 8)];
            }
            #pragma unroll
            for (int mi = 0; mi < 2; ++mi) {
                int arow = w * 32 + mi * 16 + l15;
                int so = (lg ^ (arow & 3)) * 8;
                bf16x8 ah = *(const bf16x8*)&Ah[cur][arow * GBK + so];
                #pragma unroll
                for (int ni4 = 0; ni4 < 4; ++ni4)
                    acc[mi][half * 4 + ni4] = __builtin_amdgcn_mfma_f32_16x16x32_bf16(
                        ah, bfr[ni4], acc[mi][half * 4 + ni4], 0, 0, 0);
            }
        }
        __syncthreads();
    }

    float bv8[8];
    #pragma unroll
    for (int ni = 0; ni < 8; ++ni) bv8[ni] = bias[n0 + ni * 16 + l15];

    if (zi < 2) {
        u16* __restrict__ dst = (zi == 0) ? wsq : wsk;
        #pragma unroll
        for (int mi = 0; mi < 2; ++mi) {
            #pragma unroll
            for (int r = 0; r < 4; ++r) {
                int m = m0 + w * 32 + mi * 16 + lg * 4 + r;
                int bb = m >> 11, s = m & 2047;
                #pragma unroll
                for (int ni = 0; ni < 8; ++ni) {
                    int h = h0 + (ni >> 2);
                    int hd = (ni & 3) * 16 + l15;
                    dst[((size_t)(bb * H + h) * S + s) * HD + hd] =
                        f2bf(acc[mi][ni][r] + bv8[ni]);
                }
            }
        }
    } else {
        #pragma unroll
        for (int mi = 0; mi < 2; ++mi) {
            int mb = m0 + w * 32 + mi * 16 + lg * 4;
            int bb = mb >> 11, s0 = mb & 2047;
            #pragma unroll
            for (int ni = 0; ni < 8; ++ni) {
                int h = h0 + (ni >> 2);
                int hd = (ni & 3) * 16 + l15;
                u16 e0 = f2bf(acc[mi][ni][0] + bv8[ni]);
                u16 e1 = f2bf(acc[mi][ni][1] + bv8[ni]);
                u16 e2 = f2bf(acc[mi][ni][2] + bv8[ni]);
                u16 e3 = f2bf(acc[mi][ni][3] + bv8[ni]);
                *(uint2*)(wvt + ((size_t)(bb * H + h) * HD + hd) * S + s0) =
                    make_uint2(pack2(e0, e1), pack2(e2, e3));
            }
        }
    }
}

// ---------------------------------------------------------------------------
// Kernel 2: fused attention (swapped QK^T, 2-pass, QB=256, 16 waves, T5
// setprio, nt probs stores). Unchanged from R12.
// ---------------------------------------------------------------------------
__global__ __launch_bounds__(1024) void attn_fused_kernel(
    const u16* __restrict__ qg, const u16* __restrict__ kg,
    const u16* __restrict__ vtg, float* __restrict__ probs,
    float* __restrict__ out)
{
    // XCD-aware remap (nwg = 512, divisible by 8 -> bijective; chunk 64)
    const int lin = blockIdx.x;
    const int swz = (lin & 7) * 64 + (lin >> 3);
    const int bh = swz >> 3;                  // 8 q-blocks per bh
    const int m0 = (swz & 7) * 256;

    const int b = bh >> 4, h = bh & 15;
    const int tid = threadIdx.x;
    const int w = tid >> 6, lane = tid & 63;  // 16 waves
    const int l15 = lane & 15, lg = lane >> 4;

    const u16* __restrict__ qb  = qg  + (size_t)bh * S * HD;
    const u16* __restrict__ kbp = kg  + (size_t)bh * S * HD;
    const u16* __restrict__ vtb = vtg + (size_t)bh * HD * S;
    float* __restrict__ pb = probs + ((size_t)bh * S + m0) * (size_t)S;

    __shared__ __align__(16) u16 Ks[2][64 * 64];     // 16 KB
    __shared__ __align__(16) u16 Vts[2][64 * 64];    // 16 KB
    __shared__ __align__(16) u16 Pl[16][16 * 64];    // 32 KB, wave-private

    bf16x8 aq[2];
    {
        const u16* qr = qb + (size_t)(m0 + w * 16 + l15) * HD + lg * 8;
        aq[0] = *(const bf16x8*)(qr);
        aq[1] = *(const bf16x8*)(qr + 32);
    }

    // 512 chunks per 64x64 tile; waves 0-7 stage K, waves 8-15 stage V.
    auto stageK = [&](int t, int bb) {
        if (w < 8) {
            int c = w * 64 + lane;
            int r = c >> 3, s = c & 7;
            int sc = (s ^ (r & 7)) * 8;
            gll16(kbp + (size_t)(t * 64 + r) * 64 + sc, &Ks[bb][(w * 64) * 8]);
        }
    };
    auto stageV = [&](int t, int bb) {
        if (w >= 8) {
            int c = (w - 8) * 64 + lane;
            int r = c >> 3, s = c & 7;
            int sc = (s ^ (r & 7)) * 8;
            gll16(vtb + (size_t)r * S + t * 64 + sc, &Vts[bb][((w - 8) * 64) * 8]);
        }
    };

    // ------------------------- Pass A: row sums -------------------------
    float lacc = 0.f;
    stageK(0, 0);
    __syncthreads();

    for (int t = 0; t < 32; ++t) {
        const int cur = t & 1;
        if (t < 31) stageK(t + 1, cur ^ 1);
        f32x4 acc[4];
        #pragma unroll
        for (int n = 0; n < 4; ++n) acc[n] = (f32x4){0.f, 0.f, 0.f, 0.f};
        __builtin_amdgcn_s_setprio(1);
        #pragma unroll
        for (int n = 0; n < 4; ++n) {
            #pragma unroll
            for (int kk = 0; kk < 2; ++kk) {
                int row = n * 16 + l15;
                int sl = (kk * 4 + lg) ^ (row & 7);
                bf16x8 bk_ = *(const bf16x8*)&Ks[cur][row * 64 + sl * 8];
                // SWAPPED: A = K rows, B = Q rows -> D[k][q], q = col = l15
                acc[n] = __builtin_amdgcn_mfma_f32_16x16x32_bf16(bk_, aq[kk], acc[n], 0, 0, 0);
            }
        }
        __builtin_amdgcn_s_setprio(0);
        #pragma unroll
        for (int n = 0; n < 4; ++n)
            #pragma unroll
            for (int r = 0; r < 4; ++r)
                lacc += __expf(acc[n][r]);
        __syncthreads();
    }

    lacc += __shfl_xor(lacc, 16, 64);
    lacc += __shfl_xor(lacc, 32, 64);
    const float inv_l = 1.f / lacc;          // row sum for q-row w*16+l15

    // --------------------- Pass B: probs + PV ---------------------
    f32x4 accO[4];
    #pragma unroll
    for (int n = 0; n < 4; ++n) accO[n] = (f32x4){0.f, 0.f, 0.f, 0.f};

    stageK(0, 0);
    stageV(0, 0);
    __syncthreads();

    float* pqrow = pb + (size_t)(w * 16 + l15) * S + lg * 4;   // this lane's q-row

    for (int t = 0; t < 32; ++t) {
        const int cur = t & 1;
        if (t < 31) { stageK(t + 1, cur ^ 1); stageV(t + 1, cur ^ 1); }

        f32x4 acc[4];
        #pragma unroll
        for (int n = 0; n < 4; ++n) acc[n] = (f32x4){0.f, 0.f, 0.f, 0.f};
        __builtin_amdgcn_s_setprio(1);
        #pragma unroll
        for (int n = 0; n < 4; ++n) {
            #pragma unroll
            for (int kk = 0; kk < 2; ++kk) {
                int row = n * 16 + l15;
                int sl = (kk * 4 + lg) ^ (row & 7);
                bf16x8 bk_ = *(const bf16x8*)&Ks[cur][row * 64 + sl * 8];
                acc[n] = __builtin_amdgcn_mfma_f32_16x16x32_bf16(bk_, aq[kk], acc[n], 0, 0, 0);
            }
        }
        __builtin_amdgcn_s_setprio(0);

        // p = exp(s)/l : lane owns q-row l15, k = t*64 + n*16 + lg*4 + r
        #pragma unroll
        for (int n = 0; n < 4; ++n) {
            float e0 = __expf(acc[n][0]) * inv_l;
            float e1 = __expf(acc[n][1]) * inv_l;
            float e2 = __expf(acc[n][2]) * inv_l;
            float e3 = __expf(acc[n][3]) * inv_l;
            f32x4 p4 = (f32x4){e0, e1, e2, e3};
            __builtin_nontemporal_store(p4, (f32x4*)(pqrow + t * 64 + n * 16));
            uint2 pk2 = make_uint2(pack2(f2bf(e0), f2bf(e1)),
                                   pack2(f2bf(e2), f2bf(e3)));
            int s16 = (2 * n + (lg >> 1)) ^ (l15 & 7);
            *(uint2*)&Pl[w][l15 * 64 + s16 * 8 + (lg & 1) * 4] = pk2;
        }

        // PV A-frags straight from wave-private P_lds (row = q = l15)
        bf16x8 af[2];
        #pragma unroll
        for (int kk2 = 0; kk2 < 2; ++kk2) {
            int s16 = (kk2 * 4 + lg) ^ (l15 & 7);
            af[kk2] = *(const bf16x8*)&Pl[w][l15 * 64 + s16 * 8];
        }

        __builtin_amdgcn_s_setprio(1);
        #pragma unroll
        for (int n = 0; n < 4; ++n) {
            #pragma unroll
            for (int kk2 = 0; kk2 < 2; ++kk2) {
                int row = n * 16 + l15;
                int sl = (kk2 * 4 + lg) ^ (row & 7);
                bf16x8 bv = *(const bf16x8*)&Vts[cur][row * 64 + sl * 8];
                accO[n] = __builtin_amdgcn_mfma_f32_16x16x32_bf16(af[kk2], bv, accO[n], 0, 0, 0);
            }
        }
        __builtin_amdgcn_s_setprio(0);
        __syncthreads();
    }

    // epilogue: out[b][m0 + w*16 + lg*4 + r][h*64 + n*16 + l15]
    #pragma unroll
    for (int n = 0; n < 4; ++n)
        #pragma unroll
        for (int r = 0; r < 4; ++r)
            out[((size_t)b * S + m0 + w * 16 + lg * 4 + r) * D + h * HD + n * 16 + l15] =
                accO[n][r];
}

// ---------------------------------------------------------------------------
extern "C" void kernel_launch(void* const* d_in, const int* in_sizes, int n_in,
                              void* d_out, int out_size, void* d_ws, size_t ws_size,
                              hipStream_t stream)
{
    const float* x  = (const float*)d_in[0];
    const float* Wq = (const float*)d_in[1];
    const float* bq = (const float*)d_in[2];
    const float* Wk = (const float*)d_in[3];
    const float* bk = (const float*)d_in[4];
    const float* Wv = (const float*)d_in[5];
    const float* bv = (const float*)d_in[6];

    float* out   = (float*)d_out;               // [B,S,D]
    float* probs = out + (size_t)B * S * D;     // [B,H,S,S]

    u16* wsq = (u16*)d_ws;                      // bf16 q [B,H,S,HD]
    u16* wsk = wsq + TEN;                       // bf16 k [B,H,S,HD]
    u16* wvt = wsk + TEN;                       // bf16 v^T [B,H,HD,S]
    u16* xbf = wvt + TEN;                       // bf16 x [M,D]
    u16* wbf = xbf + TEN;                       // bf16 Wq|Wk|Wv [3,D,D]
    (void)ws_size;                              // needs (4*TEN + 3*D*D)*2 ~= 73.4 MB

    dim3 gc((unsigned)((NX8 + 3 * NW8 + 255) / 256));
    convert_kernel<<<gc, 256, 0, stream>>>(x, Wq, Wk, Wv, xbf, wbf);

    qkv_proj_kernel<<<dim3(1536), 256, 0, stream>>>(xbf, wbf, bq, bk, bv,
                                                    wsq, wsk, wvt);

    attn_fused_kernel<<<dim3(512), 1024, 0, stream>>>(wsq, wsk, wvt, probs, out);
}

// Round 14
// 419.786 us; speedup vs baseline: 2.6322x; 1.0034x over previous
//
#include <hip/hip_runtime.h>
#include <hip/hip_bf16.h>

typedef unsigned short u16;
typedef unsigned int   u32;

// Problem constants: B=4, S=2048, D=1024, H=16, HD=64
constexpr int B = 4, S = 2048, D = 1024, H = 16, HD = 64;
constexpr int M = B * S;                    // 8192
constexpr size_t TEN = (size_t)M * D;       // elems per q/k/v tensor (8.4M)

using bf16x8 = __attribute__((ext_vector_type(8))) short;
using f32x4  = __attribute__((ext_vector_type(4))) float;

__device__ __forceinline__ u16 f2bf(float f) {      // RNE f32 -> bf16
    u32 u = __float_as_uint(f);
    u += 0x7fffu + ((u >> 16) & 1u);
    return (u16)(u >> 16);
}
__device__ __forceinline__ u32 pack2(u16 a, u16 b) { return (u32)a | ((u32)b << 16); }

// Async global->LDS, 16B per lane. LDS dest is the WAVE-UNIFORM base;
// HW writes lane i at base + i*16. Source addr is per-lane.
__device__ __forceinline__ void gll16(const u16* gsrc, u16* ldst) {
    __builtin_amdgcn_global_load_lds(
        (const __attribute__((address_space(1))) u32*)gsrc,
        (__attribute__((address_space(3))) u32*)ldst,
        16, 0, 0);
}

// ---------------------------------------------------------------------------
// Kernel 0: convert x -> bf16 and Wq|Wk|Wv -> bf16. Unchanged from R13.
// ---------------------------------------------------------------------------
constexpr size_t NX8 = TEN / 8;             // 1,048,576 x-chunks
constexpr size_t NW8 = (size_t)D * D / 8;   // 131,072 chunks per W

__global__ __launch_bounds__(256) void convert_kernel(
    const float* __restrict__ x,
    const float* __restrict__ Wq, const float* __restrict__ Wk,
    const float* __restrict__ Wv,
    u16* __restrict__ xbf, u16* __restrict__ wbf)
{
    size_t i = (size_t)blockIdx.x * 256 + threadIdx.x;
    if (i < NX8) {
        float4 f0 = *((const float4*)x + i * 2);
        float4 f1 = *((const float4*)x + i * 2 + 1);
        float f[8] = {f0.x, f0.y, f0.z, f0.w, f1.x, f1.y, f1.z, f1.w};
        u16 h[8];
        #pragma unroll
        for (int e = 0; e < 8; ++e) h[e] = f2bf(f[e]);
        *(uint4*)(xbf + i * 8) = make_uint4(pack2(h[0],h[1]), pack2(h[2],h[3]),
                                            pack2(h[4],h[5]), pack2(h[6],h[7]));
    } else if (i < NX8 + 3 * NW8) {
        size_t j = i - NX8;
        const float* Wsrc;
        size_t jj;
        if (j < NW8)            { Wsrc = Wq; jj = j; }
        else if (j < 2 * NW8)   { Wsrc = Wk; jj = j - NW8; }
        else                    { Wsrc = Wv; jj = j - 2 * NW8; }
        float4 f0 = *((const float4*)Wsrc + jj * 2);
        float4 f1 = *((const float4*)Wsrc + jj * 2 + 1);
        float f[8] = {f0.x, f0.y, f0.z, f0.w, f1.x, f1.y, f1.z, f1.w};
        u16 h[8];
        #pragma unroll
        for (int e = 0; e < 8; ++e) h[e] = f2bf(f[e]);
        *(uint4*)(wbf + j * 8) = make_uint4(pack2(h[0],h[1]), pack2(h[2],h[3]),
                                            pack2(h[4],h[5]), pack2(h[6],h[7]));
    }
}

// ---------------------------------------------------------------------------
// Kernel 1: QKV projection via bf16 MFMA. Unchanged from R13.
// ---------------------------------------------------------------------------
constexpr int GBM = 128, GBN = 128, GBK = 32;
constexpr int NKT = D / GBK;                 // 32 k-tiles

__global__ __launch_bounds__(256, 3) void qkv_proj_kernel(
    const u16* __restrict__ xbf, const u16* __restrict__ wbf,
    const float* __restrict__ bq, const float* __restrict__ bk,
    const float* __restrict__ bv,
    u16* __restrict__ wsq, u16* __restrict__ wsk, u16* __restrict__ wvt)
{
    const int lin    = blockIdx.x;            // 0..1535
    const int xcd    = lin & 7;
    const int local  = lin >> 3;              // 0..191
    const int wg     = local >> 3;            // 0..23 : (zi,ny)
    const int zi     = wg >> 3;               // 0..2
    const int ny     = wg & 7;                // 0..7
    const int mstrip = xcd * 8 + (local & 7); // 0..63

    const u16* __restrict__ Wz = wbf + (size_t)zi * D * D;
    const float* __restrict__ bias = (zi == 0) ? bq : (zi == 1) ? bk : bv;

    const int m0 = mstrip * GBM;
    const int n0 = ny * GBN;                  // spans heads n0/64, n0/64+1
    const int h0 = n0 >> 6;
    const int tid = threadIdx.x;
    const int w = tid >> 6, lane = tid & 63;
    const int l15 = lane & 15, lg = lane >> 4;

    __shared__ __align__(16) u16 Ah[2][GBM * GBK];   // 2 x 8KB
    __shared__ __align__(16) u16 Bt[2][GBN * GBK];   // 2 x 8KB

    const u16* __restrict__ xb_b = xbf + (size_t)m0 * D;
    const u16* __restrict__ wz_b = Wz + (size_t)n0 * D;

    f32x4 acc[2][8];
    #pragma unroll
    for (int mi = 0; mi < 2; ++mi)
        #pragma unroll
        for (int ni = 0; ni < 8; ++ni) acc[mi][ni] = (f32x4){0.f,0.f,0.f,0.f};

    auto stage = [&](int kt, int bb) {
        const int kofs = kt * GBK;
        #pragma unroll
        for (int p = 0; p < 2; ++p) {
            int c = w * 128 + p * 64 + lane;
            int r = c >> 2, s = c & 3;
            int sc = (s ^ (r & 3)) * 8;               // inverse swizzle on source
            const size_t go = (size_t)r * D + kofs + sc;
            gll16(xb_b + go, &Ah[bb][(w * 128 + p * 64) * 8]);
            gll16(wz_b + go, &Bt[bb][(w * 128 + p * 64) * 8]);
        }
    };

    stage(0, 0);
    __syncthreads();

    for (int kt = 0; kt < NKT; ++kt) {
        const int cur = kt & 1;
        if (kt < NKT - 1) stage(kt + 1, cur ^ 1);

        #pragma unroll
        for (int half = 0; half < 2; ++half) {
            bf16x8 bfr[4];
            #pragma unroll
            for (int ni4 = 0; ni4 < 4; ++ni4) {
                int brow = (half * 4 + ni4) * 16 + l15;
                bfr[ni4] = *(const bf16x8*)&Bt[cur][brow * GBK + ((lg ^ (brow & 3)) * 8)];
            }
            #pragma unroll
            for (int mi = 0; mi < 2; ++mi) {
                int arow = w * 32 + mi * 16 + l15;
                int so = (lg ^ (arow & 3)) * 8;
                bf16x8 ah = *(const bf16x8*)&Ah[cur][arow * GBK + so];
                #pragma unroll
                for (int ni4 = 0; ni4 < 4; ++ni4)
                    acc[mi][half * 4 + ni4] = __builtin_amdgcn_mfma_f32_16x16x32_bf16(
                        ah, bfr[ni4], acc[mi][half * 4 + ni4], 0, 0, 0);
            }
        }
        __syncthreads();
    }

    float bv8[8];
    #pragma unroll
    for (int ni = 0; ni < 8; ++ni) bv8[ni] = bias[n0 + ni * 16 + l15];

    if (zi < 2) {
        u16* __restrict__ dst = (zi == 0) ? wsq : wsk;
        #pragma unroll
        for (int mi = 0; mi < 2; ++mi) {
            #pragma unroll
            for (int r = 0; r < 4; ++r) {
                int m = m0 + w * 32 + mi * 16 + lg * 4 + r;
                int bb = m >> 11, s = m & 2047;
                #pragma unroll
                for (int ni = 0; ni < 8; ++ni) {
                    int h = h0 + (ni >> 2);
                    int hd = (ni & 3) * 16 + l15;
                    dst[((size_t)(bb * H + h) * S + s) * HD + hd] =
                        f2bf(acc[mi][ni][r] + bv8[ni]);
                }
            }
        }
    } else {
        #pragma unroll
        for (int mi = 0; mi < 2; ++mi) {
            int mb = m0 + w * 32 + mi * 16 + lg * 4;
            int bb = mb >> 11, s0 = mb & 2047;
            #pragma unroll
            for (int ni = 0; ni < 8; ++ni) {
                int h = h0 + (ni >> 2);
                int hd = (ni & 3) * 16 + l15;
                u16 e0 = f2bf(acc[mi][ni][0] + bv8[ni]);
                u16 e1 = f2bf(acc[mi][ni][1] + bv8[ni]);
                u16 e2 = f2bf(acc[mi][ni][2] + bv8[ni]);
                u16 e3 = f2bf(acc[mi][ni][3] + bv8[ni]);
                *(uint2*)(wvt + ((size_t)(bb * H + h) * HD + hd) * S + s0) =
                    make_uint2(pack2(e0, e1), pack2(e2, e3));
            }
        }
    }
}

// ---------------------------------------------------------------------------
// Kernel 2: fused attention (swapped QK^T, 2-pass, QB=256, 16 waves, T5
// setprio, nt probs stores). R14: 3-deep K/V buffers with COUNTED vmcnt +
// raw s_barrier (T3/T4, m201 pattern) -- prefetch for t+2 stays in flight
// ACROSS the barrier instead of the compiler's per-tile vmcnt(0) drain.
// Soundness: vmcnt retires in issue order; per iter (pass B) ops newer than
// the t+1 load are {1 prefetch + 4 nt stores} -> vmcnt(5); pass A -> vmcnt(1).
// Recycled buffer (t+2)%3 was fully read at t-1 (LDS reads are synchronous,
// fenced by that iteration's barrier). LDS 80KB -> 2 blocks/CU (160KB exact).
// ---------------------------------------------------------------------------
__global__ __launch_bounds__(1024) void attn_fused_kernel(
    const u16* __restrict__ qg, const u16* __restrict__ kg,
    const u16* __restrict__ vtg, float* __restrict__ probs,
    float* __restrict__ out)
{
    // XCD-aware remap (nwg = 512, divisible by 8 -> bijective; chunk 64)
    const int lin = blockIdx.x;
    const int swz = (lin & 7) * 64 + (lin >> 3);
    const int bh = swz >> 3;                  // 8 q-blocks per bh
    const int m0 = (swz & 7) * 256;

    const int b = bh >> 4, h = bh & 15;
    const int tid = threadIdx.x;
    const int w = tid >> 6, lane = tid & 63;  // 16 waves
    const int l15 = lane & 15, lg = lane >> 4;

    const u16* __restrict__ qb  = qg  + (size_t)bh * S * HD;
    const u16* __restrict__ kbp = kg  + (size_t)bh * S * HD;
    const u16* __restrict__ vtb = vtg + (size_t)bh * HD * S;
    float* __restrict__ pb = probs + ((size_t)bh * S + m0) * (size_t)S;

    __shared__ __align__(16) u16 Ks[3][64 * 64];     // 24 KB
    __shared__ __align__(16) u16 Vts[3][64 * 64];    // 24 KB
    __shared__ __align__(16) u16 Pl[16][16 * 64];    // 32 KB, wave-private

    bf16x8 aq[2];
    {
        const u16* qr = qb + (size_t)(m0 + w * 16 + l15) * HD + lg * 8;
        aq[0] = *(const bf16x8*)(qr);
        aq[1] = *(const bf16x8*)(qr + 32);
    }

    // 512 chunks per 64x64 tile; waves 0-7 stage K, waves 8-15 stage V.
    auto stageK = [&](int t, int bb) {
        if (w < 8) {
            int c = w * 64 + lane;
            int r = c >> 3, s = c & 7;
            int sc = (s ^ (r & 7)) * 8;
            gll16(kbp + (size_t)(t * 64 + r) * 64 + sc, &Ks[bb][(w * 64) * 8]);
        }
    };
    auto stageV = [&](int t, int bb) {
        if (w >= 8) {
            int c = (w - 8) * 64 + lane;
            int r = c >> 3, s = c & 7;
            int sc = (s ^ (r & 7)) * 8;
            gll16(vtb + (size_t)r * S + t * 64 + sc, &Vts[bb][((w - 8) * 64) * 8]);
        }
    };

    // ------------------------- Pass A: row sums -------------------------
    float lacc = 0.f;
    stageK(0, 0);
    stageK(1, 1);
    asm volatile("s_waitcnt vmcnt(1)" ::: "memory");   // tile-0 K landed
    __builtin_amdgcn_s_barrier();
    __builtin_amdgcn_sched_barrier(0);

    {
        int cur = 0, stg = 2;
        for (int t = 0; t < 32; ++t) {
            if (t < 30) stageK(t + 2, stg);
            f32x4 acc[4];
            #pragma unroll
            for (int n = 0; n < 4; ++n) acc[n] = (f32x4){0.f, 0.f, 0.f, 0.f};
            __builtin_amdgcn_s_setprio(1);
            #pragma unroll
            for (int n = 0; n < 4; ++n) {
                #pragma unroll
                for (int kk = 0; kk < 2; ++kk) {
                    int row = n * 16 + l15;
                    int sl = (kk * 4 + lg) ^ (row & 7);
                    bf16x8 bk_ = *(const bf16x8*)&Ks[cur][row * 64 + sl * 8];
                    // SWAPPED: A = K rows, B = Q rows -> D[k][q], q = col = l15
                    acc[n] = __builtin_amdgcn_mfma_f32_16x16x32_bf16(bk_, aq[kk], acc[n], 0, 0, 0);
                }
            }
            __builtin_amdgcn_s_setprio(0);
            #pragma unroll
            for (int n = 0; n < 4; ++n)
                #pragma unroll
                for (int r = 0; r < 4; ++r)
                    lacc += __expf(acc[n][r]);
            // wait own t+1 K load (1 newer op = t+2's), publish, fence.
            if (t < 30)      asm volatile("s_waitcnt vmcnt(1)" ::: "memory");
            else if (t == 30) asm volatile("s_waitcnt vmcnt(0)" ::: "memory");
            __builtin_amdgcn_s_barrier();
            __builtin_amdgcn_sched_barrier(0);
            cur = (cur == 2) ? 0 : cur + 1;
            stg = (stg == 2) ? 0 : stg + 1;
        }
    }

    lacc += __shfl_xor(lacc, 16, 64);
    lacc += __shfl_xor(lacc, 32, 64);
    const float inv_l = 1.f / lacc;          // row sum for q-row w*16+l15

    // --------------------- Pass B: probs + PV ---------------------
    f32x4 accO[4];
    #pragma unroll
    for (int n = 0; n < 4; ++n) accO[n] = (f32x4){0.f, 0.f, 0.f, 0.f};

    stageK(0, 0); stageV(0, 0);
    stageK(1, 1); stageV(1, 1);
    asm volatile("s_waitcnt vmcnt(1)" ::: "memory");   // tile-0 K/V landed
    __builtin_amdgcn_s_barrier();
    __builtin_amdgcn_sched_barrier(0);

    float* pqrow = pb + (size_t)(w * 16 + l15) * S + lg * 4;   // this lane's q-row

    {
        int cur = 0, stg = 2;
        for (int t = 0; t < 32; ++t) {
            if (t < 30) { stageK(t + 2, stg); stageV(t + 2, stg); }

            f32x4 acc[4];
            #pragma unroll
            for (int n = 0; n < 4; ++n) acc[n] = (f32x4){0.f, 0.f, 0.f, 0.f};
            __builtin_amdgcn_s_setprio(1);
            #pragma unroll
            for (int n = 0; n < 4; ++n) {
                #pragma unroll
                for (int kk = 0; kk < 2; ++kk) {
                    int row = n * 16 + l15;
                    int sl = (kk * 4 + lg) ^ (row & 7);
                    bf16x8 bk_ = *(const bf16x8*)&Ks[cur][row * 64 + sl * 8];
                    acc[n] = __builtin_amdgcn_mfma_f32_16x16x32_bf16(bk_, aq[kk], acc[n], 0, 0, 0);
                }
            }
            __builtin_amdgcn_s_setprio(0);

            // p = exp(s)/l : lane owns q-row l15, k = t*64 + n*16 + lg*4 + r
            #pragma unroll
            for (int n = 0; n < 4; ++n) {
                float e0 = __expf(acc[n][0]) * inv_l;
                float e1 = __expf(acc[n][1]) * inv_l;
                float e2 = __expf(acc[n][2]) * inv_l;
                float e3 = __expf(acc[n][3]) * inv_l;
                f32x4 p4 = (f32x4){e0, e1, e2, e3};
                __builtin_nontemporal_store(p4, (f32x4*)(pqrow + t * 64 + n * 16));
                uint2 pk2 = make_uint2(pack2(f2bf(e0), f2bf(e1)),
                                       pack2(f2bf(e2), f2bf(e3)));
                int s16 = (2 * n + (lg >> 1)) ^ (l15 & 7);
                *(uint2*)&Pl[w][l15 * 64 + s16 * 8 + (lg & 1) * 4] = pk2;
            }

            // PV A-frags straight from wave-private P_lds (row = q = l15)
            bf16x8 af[2];
            #pragma unroll
            for (int kk2 = 0; kk2 < 2; ++kk2) {
                int s16 = (kk2 * 4 + lg) ^ (l15 & 7);
                af[kk2] = *(const bf16x8*)&Pl[w][l15 * 64 + s16 * 8];
            }

            __builtin_amdgcn_s_setprio(1);
            #pragma unroll
            for (int n = 0; n < 4; ++n) {
                #pragma unroll
                for (int kk2 = 0; kk2 < 2; ++kk2) {
                    int row = n * 16 + l15;
                    int sl = (kk2 * 4 + lg) ^ (row & 7);
                    bf16x8 bv = *(const bf16x8*)&Vts[cur][row * 64 + sl * 8];
                    accO[n] = __builtin_amdgcn_mfma_f32_16x16x32_bf16(af[kk2], bv, accO[n], 0, 0, 0);
                }
            }
            __builtin_amdgcn_s_setprio(0);

            // wait own t+1 load; newer ops = {1 prefetch, 4 nt stores} -> 5.
            if (t < 30)      asm volatile("s_waitcnt vmcnt(5)" ::: "memory");
            else if (t == 30) asm volatile("s_waitcnt vmcnt(4)" ::: "memory");
            __builtin_amdgcn_s_barrier();
            __builtin_amdgcn_sched_barrier(0);
            cur = (cur == 2) ? 0 : cur + 1;
            stg = (stg == 2) ? 0 : stg + 1;
        }
    }

    // epilogue: out[b][m0 + w*16 + lg*4 + r][h*64 + n*16 + l15]
    #pragma unroll
    for (int n = 0; n < 4; ++n)
        #pragma unroll
        for (int r = 0; r < 4; ++r)
            out[((size_t)b * S + m0 + w * 16 + lg * 4 + r) * D + h * HD + n * 16 + l15] =
                accO[n][r];
}

// ---------------------------------------------------------------------------
extern "C" void kernel_launch(void* const* d_in, const int* in_sizes, int n_in,
                              void* d_out, int out_size, void* d_ws, size_t ws_size,
                              hipStream_t stream)
{
    const float* x  = (const float*)d_in[0];
    const float* Wq = (const float*)d_in[1];
    const float* bq = (const float*)d_in[2];
    const float* Wk = (const float*)d_in[3];
    const float* bk = (const float*)d_in[4];
    const float* Wv = (const float*)d_in[5];
    const float* bv = (const float*)d_in[6];

    float* out   = (float*)d_out;               // [B,S,D]
    float* probs = out + (size_t)B * S * D;     // [B,H,S,S]

    u16* wsq = (u16*)d_ws;                      // bf16 q [B,H,S,HD]
    u16* wsk = wsq + TEN;                       // bf16 k [B,H,S,HD]
    u16* wvt = wsk + TEN;                       // bf16 v^T [B,H,HD,S]
    u16* xbf = wvt + TEN;                       // bf16 x [M,D]
    u16* wbf = xbf + TEN;                       // bf16 Wq|Wk|Wv [3,D,D]
    (void)ws_size;                              // needs (4*TEN + 3*D*D)*2 ~= 73.4 MB

    dim3 gc((unsigned)((NX8 + 3 * NW8 + 255) / 256));
    convert_kernel<<<gc, 256, 0, stream>>>(x, Wq, Wk, Wv, xbf, wbf);

    qkv_proj_kernel<<<dim3(1536), 256, 0, stream>>>(xbf, wbf, bq, bk, bv,
                                                    wsq, wsk, wvt);

    attn_fused_kernel<<<dim3(512), 1024, 0, stream>>>(wsq, wsk, wvt, probs, out);
}